// Round 8
// baseline (227.370 us; speedup 1.0000x reference)
//
#include <hip/hip_runtime.h>
#include <hip/hip_bf16.h>
#include <math.h>

#define NB 4
#define CC 128
#define HH 64
#define WW 64
#define HEADS 4
#define KS 7
#define DD 32
#define HW 4096
#define MTOT 16384   // NB*HW

typedef unsigned short BF;
typedef short short8 __attribute__((ext_vector_type(8)));
typedef float floatx4 __attribute__((ext_vector_type(4)));

__device__ __forceinline__ float gelu_f(float x) {
    return 0.5f * x * (1.0f + erff(x * 0.70710678118654752440f));
}

__device__ __forceinline__ BF f2bf(float f) {
    union { float f; unsigned u; } a; a.f = f;
    unsigned u = a.u;
    unsigned r = u + 0x7FFFu + ((u >> 16) & 1u);   // RNE
    return (BF)(r >> 16);
}

__device__ __forceinline__ float bflo(unsigned p) { return __uint_as_float(p << 16); }
__device__ __forceinline__ float bfhi(unsigned p) { return __uint_as_float(p & 0xffff0000u); }

#define LDK 40      // padded LDS row for conv H tile (bf16)

// ---------------- LN1 transpose-tile + weight prep --------------------
// blocks [0,512): LN1 NCHW -> bf16 NHWC rows (coalesced via LDS transpose)
// blocks [512,640): transpose-convert all 6 weights f32 (K,N) -> bf16 (N,K)
__global__ __launch_bounds__(256) void ln1_prep_kernel(
    const float* __restrict__ x, const float* __restrict__ w,
    const float* __restrict__ b, BF* __restrict__ out,
    float* __restrict__ part,
    const float* __restrict__ qkv_w, const float* __restrict__ conv1_w,
    const float* __restrict__ conv2_w, const float* __restrict__ proj_w,
    const float* __restrict__ fc1_w, const float* __restrict__ fc2_w,
    BF* __restrict__ qkvT, BF* __restrict__ c1T, BF* __restrict__ c2T,
    BF* __restrict__ projT, BF* __restrict__ fc1T, BF* __restrict__ fc2T)
{
    const int blk = blockIdx.x;
    const int t  = threadIdx.x;

    if (blk >= 512) {   // ---- weight prep ----
        for (int idx = (blk - 512) * 256 + t; idx < 204800; idx += 32768) {
            if (idx < 49152) {                    // qkvT (K=128,N=384)
                int l = idx, n = l >> 7, k = l & 127;
                qkvT[l] = f2bf(qkv_w[k * 384 + n]);
            } else if (idx < 53248) {             // conv1T (K=128,N=32)
                int l = idx - 49152, n = l >> 7, k = l & 127;
                c1T[l] = f2bf(conv1_w[k * 32 + n]);
            } else if (idx < 57344) {             // conv2T (K=32,N=128)
                int l = idx - 53248, n = l >> 5, k = l & 31;
                c2T[l] = f2bf(conv2_w[k * 128 + n]);
            } else if (idx < 73728) {             // projT (K=128,N=128)
                int l = idx - 57344, n = l >> 7, k = l & 127;
                projT[l] = f2bf(proj_w[k * 128 + n]);
            } else if (idx < 139264) {            // fc1T (K=128,N=512)
                int l = idx - 73728, n = l >> 7, k = l & 127;
                fc1T[l] = f2bf(fc1_w[k * 512 + n]);
            } else {                              // fc2T (K=512,N=128)
                int l = idx - 139264, n = l >> 9, k = l & 511;
                fc2T[l] = f2bf(fc2_w[k * 128 + n]);
            }
        }
        return;
    }

    __shared__ float xt[128][33];
    __shared__ float mus[32], rss[32];
    const int n  = blk >> 7;
    const int p0 = (blk & 127) * 32;
    if (blk < 4 && t < 128) part[blk * CC + t] = 0.f;   // zero CA partials

    {
        int pp = t & 31, c8 = t >> 5;
        #pragma unroll 4
        for (int it = 0; it < 16; it++) {
            int c = it * 8 + c8;
            xt[c][pp] = x[(size_t)(n * CC + c) * HW + p0 + pp];
        }
    }
    __syncthreads();
    {
        int pp2 = t >> 3, cb = t & 7;
        float s = 0.f;
        #pragma unroll
        for (int u = 0; u < 16; u++) s += xt[cb + u * 8][pp2];
        s += __shfl_xor(s, 1); s += __shfl_xor(s, 2); s += __shfl_xor(s, 4);
        float mu = s * (1.0f / CC);
        float v = 0.f;
        #pragma unroll
        for (int u = 0; u < 16; u++) { float d = xt[cb + u * 8][pp2] - mu; v += d * d; }
        v += __shfl_xor(v, 1); v += __shfl_xor(v, 2); v += __shfl_xor(v, 4);
        if (cb == 0) { mus[pp2] = mu; rss[pp2] = rsqrtf(v * (1.0f / CC) + 1e-5f); }
    }
    __syncthreads();
    {
        #pragma unroll
        for (int it = 0; it < 2; it++) {
            int pp2 = (t >> 4) + it * 16;
            int c0  = (t & 15) * 8;
            float mu = mus[pp2], rs = rss[pp2];
            int m = n * HW + p0 + pp2;
            short8 o;
            #pragma unroll
            for (int u = 0; u < 8; u++)
                o[u] = (short)f2bf((xt[c0 + u][pp2] - mu) * rs * w[c0 + u] + b[c0 + u]);
            *(short8*)(out + (size_t)m * CC + c0) = o;
        }
    }
}

// ---------------- phase2: qkv GEMM + conv-MLP (direct B frags) --------
// blocks [0,1536): qkv (M,128)@(128,384) -> bf16, no LDS, no barrier
// blocks [1536,1792): conv1+gelu+conv2 -> t f32 + column sums into part
__global__ __launch_bounds__(256) void phase2(
    const BF* __restrict__ xn, const BF* __restrict__ qkvT,
    const float* __restrict__ qkv_b, BF* __restrict__ qkv_out,
    const BF* __restrict__ c1T, const float* __restrict__ b1,
    const BF* __restrict__ c2T, const float* __restrict__ b2,
    float* __restrict__ tout, float* __restrict__ part)
{
    __shared__ __align__(16) BF Hl[64][LDK];     // 5 KB (conv branch)
    __shared__ float red[4][128];                // 2 KB
    const int bid = blockIdx.x;
    const int t = threadIdx.x;
    const int w = t >> 6, lane = t & 63, q = lane >> 4, r16 = lane & 15;

    if (bid < 1536) {
        const int col0 = (bid % 6) * 64;
        const int row0 = (bid / 6) * 64;
        floatx4 acc[4] = {};
        const BF* arow = xn + (size_t)(row0 + w * 16 + r16) * CC;
        #pragma unroll
        for (int ks = 0; ks < 4; ks++) {
            short8 af = *(const short8*)(arow + ks * 32 + q * 8);
            #pragma unroll
            for (int nt = 0; nt < 4; nt++) {
                short8 bf = *(const short8*)(qkvT + (size_t)(col0 + nt * 16 + r16) * CC + ks * 32 + q * 8);
                acc[nt] = __builtin_amdgcn_mfma_f32_16x16x32_bf16(af, bf, acc[nt], 0, 0, 0);
            }
        }
        #pragma unroll
        for (int nt = 0; nt < 4; nt++) {
            int col = col0 + nt * 16 + r16;
            float bv = qkv_b[col];
            #pragma unroll
            for (int reg = 0; reg < 4; reg++) {
                int row = row0 + w * 16 + q * 4 + reg;
                qkv_out[(size_t)row * 384 + col] = f2bf(acc[nt][reg] + bv);
            }
        }
        return;
    }
    // ---- conv branch ----
    const int row0 = (bid - 1536) * 64;
    const BF* arow = xn + (size_t)(row0 + w * 16 + r16) * CC;
    floatx4 a1[2] = {};
    #pragma unroll
    for (int ks = 0; ks < 4; ks++) {
        short8 af = *(const short8*)(arow + ks * 32 + q * 8);
        #pragma unroll
        for (int nt = 0; nt < 2; nt++) {
            short8 bf = *(const short8*)(c1T + (size_t)(nt * 16 + r16) * CC + ks * 32 + q * 8);
            a1[nt] = __builtin_amdgcn_mfma_f32_16x16x32_bf16(af, bf, a1[nt], 0, 0, 0);
        }
    }
    #pragma unroll
    for (int nt = 0; nt < 2; nt++) {
        int col = nt * 16 + r16;
        float bv = b1[col];
        #pragma unroll
        for (int reg = 0; reg < 4; reg++)
            Hl[w * 16 + q * 4 + reg][col] = f2bf(gelu_f(a1[nt][reg] + bv));
    }
    __syncthreads();
    floatx4 a2[8] = {};
    short8 af2 = *(const short8*)(&Hl[w * 16 + r16][q * 8]);
    #pragma unroll
    for (int nt = 0; nt < 8; nt++) {
        short8 bf = *(const short8*)(c2T + (size_t)(nt * 16 + r16) * 32 + q * 8);
        a2[nt] = __builtin_amdgcn_mfma_f32_16x16x32_bf16(af2, bf, a2[nt], 0, 0, 0);
    }
    #pragma unroll
    for (int nt = 0; nt < 8; nt++) {
        int col = nt * 16 + r16;
        float bv = b2[col];
        float s = 0.f;
        #pragma unroll
        for (int reg = 0; reg < 4; reg++) {
            int row = row0 + w * 16 + q * 4 + reg;
            float v = a2[nt][reg] + bv;
            tout[(size_t)row * CC + col] = v;
            s += v;
        }
        s += __shfl_xor(s, 16);
        s += __shfl_xor(s, 32);
        if (lane < 16) red[w][col] = s;
    }
    __syncthreads();
    if (t < 128) {
        float cs = red[0][t] + red[1][t] + red[2][t] + red[3][t];
        atomicAdd(&part[(row0 >> 12) * CC + t], cs);
    }
}

// ---------------- tiled neighborhood attention (bf16 qkv in/out) ------
__global__ __launch_bounds__(512) void na_tile_kernel(
    const BF* __restrict__ qkv, const float* __restrict__ rpb,
    unsigned* __restrict__ outp)
{
    __shared__ unsigned Kb32[16][210];
    __shared__ unsigned Vb32[196][16];
    __shared__ unsigned Qb32[64][16];
    __shared__ float rb[169];
    __shared__ float sp[8][64];

    const int b    = blockIdx.x;
    const int h    = b & 3;
    const int tile = b >> 2;
    const int n    = tile >> 6;
    const int ti   = (tile >> 3) & 7;
    const int tj   = tile & 7;
    const int t    = threadIdx.x;
    const int w    = t >> 6;
    const int lane = t & 63;

    const int i0 = ti * 8, j0 = tj * 8;
    const int wi0 = max(i0 - 3, 0);
    const int wj0 = max(j0 - 3, 0);
    const int R  = min(wi0 + 13, HH - 1) - wi0 + 1;
    const int Rj = min(wj0 + 13, WW - 1) - wj0 + 1;

    for (int idx = t; idx < 196 * 8; idx += 512) {
        int pixel = idx >> 3, ch = idx & 7;
        int pr = pixel / 14, pc = pixel % 14;
        if (pr < R && pc < Rj) {
            int seg = ch >> 2, c4 = ch & 3;
            const BF* src = qkv
                + ((size_t)((n * HH + wi0 + pr) * WW + wj0 + pc)) * 384
                + 128 + seg * 128 + h * DD + c4 * 8;
            uint4 v = *(const uint4*)src;
            if (seg == 0) {
                Kb32[c4 * 4 + 0][pixel] = v.x;
                Kb32[c4 * 4 + 1][pixel] = v.y;
                Kb32[c4 * 4 + 2][pixel] = v.z;
                Kb32[c4 * 4 + 3][pixel] = v.w;
            } else {
                *(uint4*)&Vb32[pixel][c4 * 4] = v;
            }
        }
    }
    for (int idx = t; idx < 64 * 4; idx += 512) {
        int q = idx >> 2, c4 = idx & 3;
        int qi = q >> 3, qj = q & 7;
        size_t m = (size_t)((n * HH + i0 + qi) * WW + j0 + qj);
        *(uint4*)&Qb32[q][c4 * 4] = *(const uint4*)(qkv + m * 384 + h * DD + c4 * 8);
    }
    if (t < 169) rb[t] = rpb[h * 169 + t];
    __syncthreads();

    for (int qq = 0; qq < 8; qq++) {
        int q  = w * 8 + qq;
        int qi = q >> 3, qj = q & 7;
        int i = i0 + qi, j = j0 + qj;
        int ni = min(max(i - 3, 0), HH - KS);
        int nj = min(max(j - 3, 0), WW - KS);
        int keybase = (ni - wi0) * 14 + (nj - wj0);

        unsigned qp[16];
        #pragma unroll
        for (int u = 0; u < 16; u++) qp[u] = Qb32[q][u];

        int aa = min(lane, KS * KS - 1);
        int ar = aa / KS, ac = aa % KS;
        int key = keybase + ar * 14 + ac;
        float s = 0.f;
        #pragma unroll
        for (int dp = 0; dp < 16; dp++) {
            unsigned kv = Kb32[dp][key];
            s += bflo(qp[dp]) * bflo(kv);
            s += bfhi(qp[dp]) * bfhi(kv);
        }
        s = s * 0.17677669529663688110f + rb[(ni - i + 6 + ar) * 13 + (nj - j + 6 + ac)];
        float score = (lane < KS * KS) ? s : -INFINITY;

        float mx = score;
        #pragma unroll
        for (int off = 32; off; off >>= 1) mx = fmaxf(mx, __shfl_xor(mx, off));
        float e = (lane < KS * KS) ? __expf(score - mx) : 0.f;
        float sm = e;
        #pragma unroll
        for (int off = 32; off; off >>= 1) sm += __shfl_xor(sm, off);
        sp[w][lane] = e / sm;

        int quarter = lane >> 4, dpv = lane & 15;
        float accl = 0.f, acch = 0.f;
        int rr = 0, cc = quarter;
        #pragma unroll
        for (int it = 0; it < 13; it++) {
            int a4 = 4 * it + quarter;
            if (a4 < 49) {
                float p = sp[w][a4];
                unsigned pv = Vb32[keybase + rr * 14 + cc][dpv];
                accl += p * bflo(pv);
                acch += p * bfhi(pv);
            }
            cc += 4; if (cc >= KS) { cc -= KS; rr++; }
        }
        accl += __shfl_xor(accl, 16); accl += __shfl_xor(accl, 32);
        acch += __shfl_xor(acch, 16); acch += __shfl_xor(acch, 32);
        if (lane < 16) {
            size_t m = (size_t)((n * HH + i) * WW + j);
            unsigned pk = ((unsigned)f2bf(accl)) | (((unsigned)f2bf(acch)) << 16);
            outp[m * 64 + h * 16 + dpv] = pk;
        }
    }
}

// ---------------- CA gate + proj (direct B) + x2 + LN2 ----------------
// BM=32, grid 512 (2 blocks/CU). Wave w: m-tile (w&1), n-half (w>>1).
// Cross-wave LN reduce via LDS.
__global__ __launch_bounds__(256) void projx2ln2(
    const BF* __restrict__ A, const BF* __restrict__ projT,
    const float* __restrict__ bias, const float* __restrict__ x,
    const float* __restrict__ tbuf, const float* __restrict__ part,
    const float* __restrict__ ca1_w, const float* __restrict__ ca1_b,
    const float* __restrict__ ca2_w, const float* __restrict__ ca2_b,
    const float* __restrict__ w2, const float* __restrict__ b2,
    float* __restrict__ x2b, BF* __restrict__ lnout)
{
    __shared__ float gs[128], h1[7], gl[128];
    __shared__ float S1[4][16], S2[4][16];

    const int t = threadIdx.x;
    const int w = t >> 6, lane = t & 63, q = lane >> 4, r16 = lane & 15;
    const int row0 = blockIdx.x * 32;
    const int n = row0 >> 12;
    const int mt = w & 1, nh = w >> 1;

    if (t < 128) gs[t] = part[n * CC + t] * (1.0f / HW);
    __syncthreads();
    if (t < 7) {
        float a = ca1_b[t];
        for (int k = 0; k < 128; k++) a += gs[k] * ca1_w[k * 7 + t];
        h1[t] = fmaxf(a, 0.f);
    }
    __syncthreads();
    if (t < 128) {
        float o = ca2_b[t];
        #pragma unroll
        for (int r = 0; r < 7; r++) o += h1[r] * ca2_w[r * 128 + t];
        gl[t] = 1.0f / (1.0f + expf(-o));
    }

    floatx4 acc[4] = {};
    const BF* arow = A + (size_t)(row0 + mt * 16 + r16) * CC;
    #pragma unroll
    for (int ks = 0; ks < 4; ks++) {
        short8 af = *(const short8*)(arow + ks * 32 + q * 8);
        #pragma unroll
        for (int nt = 0; nt < 4; nt++) {
            short8 bf = *(const short8*)(projT + (size_t)(nh * 64 + nt * 16 + r16) * CC + ks * 32 + q * 8);
            acc[nt] = __builtin_amdgcn_mfma_f32_16x16x32_bf16(af, bf, acc[nt], 0, 0, 0);
        }
    }
    __syncthreads();   // gl ready

    float s1[4] = {0.f, 0.f, 0.f, 0.f}, s2[4] = {0.f, 0.f, 0.f, 0.f};
    #pragma unroll
    for (int nt = 0; nt < 4; nt++) {
        int col = nh * 64 + nt * 16 + r16;
        float bv = bias[col];
        float gv = gl[col];
        #pragma unroll
        for (int reg = 0; reg < 4; reg++) {
            int row = row0 + mt * 16 + q * 4 + reg;
            int p = row & 4095;
            float xv = x[(size_t)(n * CC + col) * HW + p];
            float tv = tbuf[(size_t)row * CC + col];
            float v = acc[nt][reg] + bv + xv + 0.02f * tv * gv;
            acc[nt][reg] = v;
            s1[reg] += v;
            s2[reg] += v * v;
        }
    }
    #pragma unroll
    for (int reg = 0; reg < 4; reg++) {
        #pragma unroll
        for (int off = 1; off < 16; off <<= 1) {
            s1[reg] += __shfl_xor(s1[reg], off);
            s2[reg] += __shfl_xor(s2[reg], off);
        }
    }
    if (r16 == 0) {
        #pragma unroll
        for (int reg = 0; reg < 4; reg++) {
            S1[w][q * 4 + reg] = s1[reg];
            S2[w][q * 4 + reg] = s2[reg];
        }
    }
    __syncthreads();
    const int pw = w ^ 2;
    float mu[4], rr[4];
    #pragma unroll
    for (int reg = 0; reg < 4; reg++) {
        int r = q * 4 + reg;
        float t1 = S1[w][r] + S1[pw][r];
        float t2 = S2[w][r] + S2[pw][r];
        mu[reg] = t1 * (1.0f / CC);
        float var = t2 * (1.0f / CC) - mu[reg] * mu[reg];
        rr[reg] = rsqrtf(var + 1e-5f);
    }
    #pragma unroll
    for (int nt = 0; nt < 4; nt++) {
        int col = nh * 64 + nt * 16 + r16;
        float wv = w2[col], bv2 = b2[col];
        #pragma unroll
        for (int reg = 0; reg < 4; reg++) {
            int row = row0 + mt * 16 + q * 4 + reg;
            float v = acc[nt][reg];
            x2b[(size_t)row * CC + col] = v;
            lnout[(size_t)row * CC + col] = f2bf((v - mu[reg]) * rr[reg] * wv + bv2);
        }
    }
}

// ---------------- fc1: direct-B GEMM, K=128, gelu, bf16 out -----------
__global__ __launch_bounds__(256) void fc1_kernel(
    const BF* __restrict__ A, const BF* __restrict__ Bt,
    const float* __restrict__ bias, BF* __restrict__ Cout)
{
    const int t = threadIdx.x;
    const int w = t >> 6, lane = t & 63, q = lane >> 4, r16 = lane & 15;
    const int col0 = blockIdx.x * 64;
    const int row0 = blockIdx.y * 64;
    floatx4 acc[4] = {};
    const BF* arow = A + (size_t)(row0 + w * 16 + r16) * CC;
    #pragma unroll
    for (int ks = 0; ks < 4; ks++) {
        short8 af = *(const short8*)(arow + ks * 32 + q * 8);
        #pragma unroll
        for (int nt = 0; nt < 4; nt++) {
            short8 bf = *(const short8*)(Bt + (size_t)(col0 + nt * 16 + r16) * CC + ks * 32 + q * 8);
            acc[nt] = __builtin_amdgcn_mfma_f32_16x16x32_bf16(af, bf, acc[nt], 0, 0, 0);
        }
    }
    #pragma unroll
    for (int nt = 0; nt < 4; nt++) {
        int col = col0 + nt * 16 + r16;
        float bv = bias[col];
        #pragma unroll
        for (int reg = 0; reg < 4; reg++) {
            int row = row0 + w * 16 + q * 4 + reg;
            Cout[(size_t)row * 512 + col] = f2bf(gelu_f(acc[nt][reg] + bv));
        }
    }
}

// ---------------- fc2: direct-B GEMM, K=512, +x2b, NCHW store ---------
__global__ __launch_bounds__(256) void fc2_kernel(
    const BF* __restrict__ A, const BF* __restrict__ Bt,
    const float* __restrict__ bias, const float* __restrict__ x2b,
    float* __restrict__ out)
{
    const int t = threadIdx.x;
    const int w = t >> 6, lane = t & 63, q = lane >> 4, r16 = lane & 15;
    const int col0 = blockIdx.x * 64;
    const int row0 = blockIdx.y * 64;
    floatx4 acc[4] = {};
    const BF* arow = A + (size_t)(row0 + w * 16 + r16) * 512;
    #pragma unroll
    for (int ks = 0; ks < 16; ks++) {
        short8 af = *(const short8*)(arow + ks * 32 + q * 8);
        #pragma unroll
        for (int nt = 0; nt < 4; nt++) {
            short8 bf = *(const short8*)(Bt + (size_t)(col0 + nt * 16 + r16) * 512 + ks * 32 + q * 8);
            acc[nt] = __builtin_amdgcn_mfma_f32_16x16x32_bf16(af, bf, acc[nt], 0, 0, 0);
        }
    }
    #pragma unroll
    for (int nt = 0; nt < 4; nt++) {
        int col = col0 + nt * 16 + r16;
        float bv = bias[col];
        #pragma unroll
        for (int reg = 0; reg < 4; reg++) {
            int row = row0 + w * 16 + q * 4 + reg;
            int p = row & 4095, n = row >> 12;
            out[(size_t)(n * CC + col) * HW + p] =
                acc[nt][reg] + bv + x2b[(size_t)row * CC + col];
        }
    }
}

extern "C" void kernel_launch(void* const* d_in, const int* in_sizes, int n_in,
                              void* d_out, int out_size, void* d_ws, size_t ws_size,
                              hipStream_t stream)
{
    const float* x       = (const float*)d_in[0];
    const float* ln1_w   = (const float*)d_in[1];
    const float* ln1_b   = (const float*)d_in[2];
    const float* ln2_w   = (const float*)d_in[3];
    const float* ln2_b   = (const float*)d_in[4];
    const float* qkv_w   = (const float*)d_in[5];
    const float* qkv_b   = (const float*)d_in[6];
    const float* proj_w  = (const float*)d_in[7];
    const float* proj_b  = (const float*)d_in[8];
    const float* rpb     = (const float*)d_in[9];
    const float* conv1_w = (const float*)d_in[10];
    const float* conv1_b = (const float*)d_in[11];
    const float* conv2_w = (const float*)d_in[12];
    const float* conv2_b = (const float*)d_in[13];
    const float* ca1_w   = (const float*)d_in[14];
    const float* ca1_b   = (const float*)d_in[15];
    const float* ca2_w   = (const float*)d_in[16];
    const float* ca2_b   = (const float*)d_in[17];
    const float* fc1_w   = (const float*)d_in[18];
    const float* fc1_b   = (const float*)d_in[19];
    const float* fc2_w   = (const float*)d_in[20];
    const float* fc2_b   = (const float*)d_in[21];
    float* out = (float*)d_out;

    // workspace (bytes). hbuf_bf overlays xn_bf+qkv_bf (both dead by fc1).
    char* ws = (char*)d_ws;
    BF*    xn_bf   = (BF*)(ws);                  // M*128*2 = 4 MB
    BF*    qkv_bf  = (BF*)(ws + 4194304);        // M*384*2 = 12 MB
    BF*    hbuf_bf = (BF*)(ws);                  // M*512*2 = 16 MB (overlay)
    float* t       = (float*)(ws + 16777216);    // M*128*4 = 8 MB
    float* x2b     = (float*)(ws + 25165824);    // M*128*4 = 8 MB
    BF*    na_bf   = (BF*)(ws + 33554432);       // M*128*2 = 4 MB
    BF*    ln2_bf  = (BF*)(ws + 37748736);       // M*128*2 = 4 MB
    float* part    = (float*)(ws + 41943040);    // 2 KB
    BF*    qkvT    = (BF*)(ws + 41945088);       // 98304 B
    BF*    c1T     = (BF*)(ws + 42043392);       // 8192 B
    BF*    c2T     = (BF*)(ws + 42051584);       // 8192 B
    BF*    projT   = (BF*)(ws + 42059776);       // 32768 B
    BF*    fc1T    = (BF*)(ws + 42092544);       // 131072 B
    BF*    fc2T    = (BF*)(ws + 42223616);       // 131072 B

    // 1. LN1 + weight transpose/convert (blocks 512..639)
    ln1_prep_kernel<<<640, 256, 0, stream>>>(x, ln1_w, ln1_b, xn_bf, part,
        qkv_w, conv1_w, conv2_w, proj_w, fc1_w, fc2_w,
        qkvT, c1T, c2T, projT, fc1T, fc2T);
    // 2. qkv GEMM (direct B, no LDS) + conv-MLP, one launch
    phase2<<<1792, 256, 0, stream>>>(xn_bf, qkvT, qkv_b, qkv_bf,
                                     c1T, conv1_b, c2T, conv2_b, t, part);
    // 3. neighborhood attention
    na_tile_kernel<<<1024, 512, 0, stream>>>(qkv_bf, rpb, (unsigned*)na_bf);
    // 4. CA gate + proj + x2 residual + LN2 (BM=32, 2 blocks/CU)
    projx2ln2<<<512, 256, 0, stream>>>(na_bf, projT, proj_b, x, t, part,
                                       ca1_w, ca1_b, ca2_w, ca2_b,
                                       ln2_w, ln2_b, x2b, ln2_bf);
    // 5. fc1 (direct B, no LDS, no barriers)
    fc1_kernel<<<dim3(8, 256), 256, 0, stream>>>(ln2_bf, fc1T, fc1_b, hbuf_bf);
    // 6. fc2 (direct B, K=512, no barriers) + x2b + NHWC->NCHW store
    fc2_kernel<<<dim3(2, 256), 256, 0, stream>>>(hbuf_bf, fc2T, fc2_b, x2b, out);
}

// Round 9
// 205.416 us; speedup vs baseline: 1.1069x; 1.1069x over previous
//
#include <hip/hip_runtime.h>
#include <hip/hip_bf16.h>
#include <math.h>

#define NB 4
#define CC 128
#define HH 64
#define WW 64
#define HEADS 4
#define KS 7
#define DD 32
#define HW 4096
#define MTOT 16384   // NB*HW

typedef unsigned short BF;
typedef short short8 __attribute__((ext_vector_type(8)));
typedef float floatx4 __attribute__((ext_vector_type(4)));

__device__ __forceinline__ float gelu_f(float x) {
    return 0.5f * x * (1.0f + erff(x * 0.70710678118654752440f));
}

__device__ __forceinline__ BF f2bf(float f) {
    union { float f; unsigned u; } a; a.f = f;
    unsigned u = a.u;
    unsigned r = u + 0x7FFFu + ((u >> 16) & 1u);   // RNE
    return (BF)(r >> 16);
}

__device__ __forceinline__ float bflo(unsigned p) { return __uint_as_float(p << 16); }
__device__ __forceinline__ float bfhi(unsigned p) { return __uint_as_float(p & 0xffff0000u); }

#define LDK 40      // padded LDS row, K=32 tiles (bf16)
#define LDK128 136  // padded LDS row, K=128 tiles (bf16)

// ---------------- LN1 transpose-tile: NCHW -> bf16 NHWC rows ----------
__global__ __launch_bounds__(256) void ln1t_kernel(
    const float* __restrict__ x, const float* __restrict__ w,
    const float* __restrict__ b, BF* __restrict__ out,
    float* __restrict__ part)
{
    __shared__ float xt[128][33];
    __shared__ float mus[32], rss[32];
    const int blk = blockIdx.x;          // 0..511
    const int n  = blk >> 7;
    const int p0 = (blk & 127) * 32;
    const int t  = threadIdx.x;
    if (blk < 4 && t < 128) part[blk * CC + t] = 0.f;   // zero CA partials

    {
        int pp = t & 31, c8 = t >> 5;
        #pragma unroll 4
        for (int it = 0; it < 16; it++) {
            int c = it * 8 + c8;
            xt[c][pp] = x[(size_t)(n * CC + c) * HW + p0 + pp];
        }
    }
    __syncthreads();
    {
        int pp2 = t >> 3, cb = t & 7;
        float s = 0.f;
        #pragma unroll
        for (int u = 0; u < 16; u++) s += xt[cb + u * 8][pp2];
        s += __shfl_xor(s, 1); s += __shfl_xor(s, 2); s += __shfl_xor(s, 4);
        float mu = s * (1.0f / CC);
        float v = 0.f;
        #pragma unroll
        for (int u = 0; u < 16; u++) { float d = xt[cb + u * 8][pp2] - mu; v += d * d; }
        v += __shfl_xor(v, 1); v += __shfl_xor(v, 2); v += __shfl_xor(v, 4);
        if (cb == 0) { mus[pp2] = mu; rss[pp2] = rsqrtf(v * (1.0f / CC) + 1e-5f); }
    }
    __syncthreads();
    {
        #pragma unroll
        for (int it = 0; it < 2; it++) {
            int pp2 = (t >> 4) + it * 16;
            int c0  = (t & 15) * 8;
            float mu = mus[pp2], rs = rss[pp2];
            int m = n * HW + p0 + pp2;
            short8 o;
            #pragma unroll
            for (int u = 0; u < 8; u++)
                o[u] = (short)f2bf((xt[c0 + u][pp2] - mu) * rs * w[c0 + u] + b[c0 + u]);
            *(short8*)(out + (size_t)m * CC + c0) = o;
        }
    }
}

// ---------------- K=128 barrier-lean GEMM body (LDS-staged B) ---------
template<int ACT>
__device__ __forceinline__ void k128_body(
    const BF* __restrict__ A, const float* __restrict__ B,
    const float* __restrict__ bias, BF* __restrict__ Cout,
    int N, int row0, int col0, BF* Bl /* [64][LDK128] */)
{
    const int t = threadIdx.x;
    const int w = t >> 6, lane = t & 63, q = lane >> 4, r16 = lane & 15;
    {   // stage B slice 128x64 -> [n][k]
        int kk = t >> 1, nn0 = (t & 1) * 32;
        const float* src = B + (size_t)kk * N + col0 + nn0;
        #pragma unroll
        for (int u = 0; u < 32; u++) Bl[(nn0 + u) * LDK128 + kk] = f2bf(src[u]);
    }
    __syncthreads();
    floatx4 acc[4] = {};
    const BF* arow = A + (size_t)(row0 + w * 16 + r16) * CC;
    #pragma unroll
    for (int ks = 0; ks < 4; ks++) {
        short8 af = *(const short8*)(arow + ks * 32 + q * 8);
        #pragma unroll
        for (int nt = 0; nt < 4; nt++) {
            short8 bf = *(const short8*)(Bl + (nt * 16 + r16) * LDK128 + ks * 32 + q * 8);
            acc[nt] = __builtin_amdgcn_mfma_f32_16x16x32_bf16(af, bf, acc[nt], 0, 0, 0);
        }
    }
    #pragma unroll
    for (int nt = 0; nt < 4; nt++) {
        int col = col0 + nt * 16 + r16;
        float bv = bias[col];
        #pragma unroll
        for (int reg = 0; reg < 4; reg++) {
            int row = row0 + w * 16 + q * 4 + reg;
            float v = acc[nt][reg] + bv;
            if (ACT == 1) v = gelu_f(v);
            Cout[(size_t)row * N + col] = f2bf(v);
        }
    }
}

// ---------------- phase2: qkv GEMM blocks + conv-MLP blocks -----------
__global__ __launch_bounds__(256) void phase2(
    const BF* __restrict__ xn, const float* __restrict__ qkv_w,
    const float* __restrict__ qkv_b, BF* __restrict__ qkv_out,
    const float* __restrict__ w1, const float* __restrict__ b1,
    const float* __restrict__ w2, const float* __restrict__ b2,
    float* __restrict__ tout, float* __restrict__ part)
{
    __shared__ __align__(16) char smem[26624];
    const int bid = blockIdx.x;
    const int t = threadIdx.x;
    const int w = t >> 6, lane = t & 63, q = lane >> 4, r16 = lane & 15;

    if (bid < 1536) {
        int col0 = (bid % 6) * 64;
        int row0 = (bid / 6) * 64;
        k128_body<0>(xn, qkv_w, qkv_b, qkv_out, 384, row0, col0, (BF*)smem);
        return;
    }
    // ---- conv branch ----
    BF*    W1l = (BF*)smem;                  // [32][LDK128]  8704 B
    BF*    W2l = (BF*)(smem + 8704);         // [128][LDK]   10240 B
    BF*    Hl  = (BF*)(smem + 18944);        // [64][LDK]     5120 B
    float* red = (float*)(smem + 24064);     // [4][128]      2048 B
    const int row0 = (bid - 1536) * 64;
    {
        int kk = t >> 1, nn = (t & 1) * 16;
        const float* src = w1 + (size_t)kk * 32 + nn;
        #pragma unroll
        for (int u = 0; u < 16; u++) W1l[(nn + u) * LDK128 + kk] = f2bf(src[u]);
    }
    {
        int kk = t >> 3, n0 = (t & 7) * 16;
        const float* src = w2 + (size_t)kk * 128 + n0;
        #pragma unroll
        for (int u = 0; u < 16; u++) W2l[(n0 + u) * LDK + kk] = f2bf(src[u]);
    }
    __syncthreads();
    floatx4 a1[2] = {};
    const BF* arow = xn + (size_t)(row0 + w * 16 + r16) * CC;
    #pragma unroll
    for (int ks = 0; ks < 4; ks++) {
        short8 af = *(const short8*)(arow + ks * 32 + q * 8);
        #pragma unroll
        for (int nt = 0; nt < 2; nt++) {
            short8 bf = *(const short8*)(W1l + (nt * 16 + r16) * LDK128 + ks * 32 + q * 8);
            a1[nt] = __builtin_amdgcn_mfma_f32_16x16x32_bf16(af, bf, a1[nt], 0, 0, 0);
        }
    }
    #pragma unroll
    for (int nt = 0; nt < 2; nt++) {
        int col = nt * 16 + r16;
        float bv = b1[col];
        #pragma unroll
        for (int reg = 0; reg < 4; reg++)
            Hl[(w * 16 + q * 4 + reg) * LDK + col] = f2bf(gelu_f(a1[nt][reg] + bv));
    }
    __syncthreads();
    floatx4 a2[8] = {};
    short8 af2 = *(const short8*)(Hl + (w * 16 + r16) * LDK + q * 8);
    #pragma unroll
    for (int nt = 0; nt < 8; nt++) {
        short8 bf = *(const short8*)(W2l + (nt * 16 + r16) * LDK + q * 8);
        a2[nt] = __builtin_amdgcn_mfma_f32_16x16x32_bf16(af2, bf, a2[nt], 0, 0, 0);
    }
    #pragma unroll
    for (int nt = 0; nt < 8; nt++) {
        int col = nt * 16 + r16;
        float bv = b2[col];
        float s = 0.f;
        #pragma unroll
        for (int reg = 0; reg < 4; reg++) {
            int row = row0 + w * 16 + q * 4 + reg;
            float v = a2[nt][reg] + bv;
            tout[(size_t)row * CC + col] = v;
            s += v;
        }
        s += __shfl_xor(s, 16);
        s += __shfl_xor(s, 32);
        if (lane < 16) red[w * 128 + col] = s;
    }
    __syncthreads();
    if (t < 128) {
        float cs = red[t] + red[128 + t] + red[256 + t] + red[384 + t];
        atomicAdd(&part[(row0 >> 12) * CC + t], cs);
    }
}

// ---------------- standalone K=128 GEMM (fc1) -------------------------
template<int ACT>
__global__ __launch_bounds__(256) void gemm_k128(
    const BF* __restrict__ A, const float* __restrict__ B,
    const float* __restrict__ bias, BF* __restrict__ Cout, int N)
{
    __shared__ __align__(16) BF Bl[64 * LDK128];
    k128_body<ACT>(A, B, bias, Cout, N, blockIdx.y * 64, blockIdx.x * 64, Bl);
}

// ---------------- tiled neighborhood attention (bf16 qkv in/out) ------
__global__ __launch_bounds__(512) void na_tile_kernel(
    const BF* __restrict__ qkv, const float* __restrict__ rpb,
    unsigned* __restrict__ outp)
{
    __shared__ unsigned Kb32[16][210];
    __shared__ unsigned Vb32[196][16];
    __shared__ unsigned Qb32[64][16];
    __shared__ float rb[169];
    __shared__ float sp[8][64];

    const int b    = blockIdx.x;
    const int h    = b & 3;
    const int tile = b >> 2;
    const int n    = tile >> 6;
    const int ti   = (tile >> 3) & 7;
    const int tj   = tile & 7;
    const int t    = threadIdx.x;
    const int w    = t >> 6;
    const int lane = t & 63;

    const int i0 = ti * 8, j0 = tj * 8;
    const int wi0 = max(i0 - 3, 0);
    const int wj0 = max(j0 - 3, 0);
    const int R  = min(wi0 + 13, HH - 1) - wi0 + 1;
    const int Rj = min(wj0 + 13, WW - 1) - wj0 + 1;

    for (int idx = t; idx < 196 * 8; idx += 512) {
        int pixel = idx >> 3, ch = idx & 7;
        int pr = pixel / 14, pc = pixel % 14;
        if (pr < R && pc < Rj) {
            int seg = ch >> 2, c4 = ch & 3;
            const BF* src = qkv
                + ((size_t)((n * HH + wi0 + pr) * WW + wj0 + pc)) * 384
                + 128 + seg * 128 + h * DD + c4 * 8;
            uint4 v = *(const uint4*)src;
            if (seg == 0) {
                Kb32[c4 * 4 + 0][pixel] = v.x;
                Kb32[c4 * 4 + 1][pixel] = v.y;
                Kb32[c4 * 4 + 2][pixel] = v.z;
                Kb32[c4 * 4 + 3][pixel] = v.w;
            } else {
                *(uint4*)&Vb32[pixel][c4 * 4] = v;
            }
        }
    }
    for (int idx = t; idx < 64 * 4; idx += 512) {
        int q = idx >> 2, c4 = idx & 3;
        int qi = q >> 3, qj = q & 7;
        size_t m = (size_t)((n * HH + i0 + qi) * WW + j0 + qj);
        *(uint4*)&Qb32[q][c4 * 4] = *(const uint4*)(qkv + m * 384 + h * DD + c4 * 8);
    }
    if (t < 169) rb[t] = rpb[h * 169 + t];
    __syncthreads();

    for (int qq = 0; qq < 8; qq++) {
        int q  = w * 8 + qq;
        int qi = q >> 3, qj = q & 7;
        int i = i0 + qi, j = j0 + qj;
        int ni = min(max(i - 3, 0), HH - KS);
        int nj = min(max(j - 3, 0), WW - KS);
        int keybase = (ni - wi0) * 14 + (nj - wj0);

        unsigned qp[16];
        #pragma unroll
        for (int u = 0; u < 16; u++) qp[u] = Qb32[q][u];

        int aa = min(lane, KS * KS - 1);
        int ar = aa / KS, ac = aa % KS;
        int key = keybase + ar * 14 + ac;
        float s = 0.f;
        #pragma unroll
        for (int dp = 0; dp < 16; dp++) {
            unsigned kv = Kb32[dp][key];
            s += bflo(qp[dp]) * bflo(kv);
            s += bfhi(qp[dp]) * bfhi(kv);
        }
        s = s * 0.17677669529663688110f + rb[(ni - i + 6 + ar) * 13 + (nj - j + 6 + ac)];
        float score = (lane < KS * KS) ? s : -INFINITY;

        float mx = score;
        #pragma unroll
        for (int off = 32; off; off >>= 1) mx = fmaxf(mx, __shfl_xor(mx, off));
        float e = (lane < KS * KS) ? __expf(score - mx) : 0.f;
        float sm = e;
        #pragma unroll
        for (int off = 32; off; off >>= 1) sm += __shfl_xor(sm, off);
        sp[w][lane] = e / sm;

        int quarter = lane >> 4, dpv = lane & 15;
        float accl = 0.f, acch = 0.f;
        int rr = 0, cc = quarter;
        #pragma unroll
        for (int it = 0; it < 13; it++) {
            int a4 = 4 * it + quarter;
            if (a4 < 49) {
                float p = sp[w][a4];
                unsigned pv = Vb32[keybase + rr * 14 + cc][dpv];
                accl += p * bflo(pv);
                acch += p * bfhi(pv);
            }
            cc += 4; if (cc >= KS) { cc -= KS; rr++; }
        }
        accl += __shfl_xor(accl, 16); accl += __shfl_xor(accl, 32);
        acch += __shfl_xor(acch, 16); acch += __shfl_xor(acch, 32);
        if (lane < 16) {
            size_t m = (size_t)((n * HH + i) * WW + j);
            unsigned pk = ((unsigned)f2bf(accl)) | (((unsigned)f2bf(acch)) << 16);
            outp[m * 64 + h * 16 + dpv] = pk;
        }
    }
}

// ---------------- fused CA-gate + proj GEMM + x2 + LN2 ----------------
// Row-complete (BM=64, BN=128). Shortcut x staged via coalesced LDS
// transpose (xs[p][c]) instead of 16KB-strided scalar gathers.
__global__ __launch_bounds__(256) void projx2ln2g(
    const BF* __restrict__ A, const float* __restrict__ Bw,
    const float* __restrict__ bias, const float* __restrict__ x,
    const float* __restrict__ tbuf, const float* __restrict__ part,
    const float* __restrict__ ca1_w, const float* __restrict__ ca1_b,
    const float* __restrict__ ca2_w, const float* __restrict__ ca2_b,
    const float* __restrict__ w2, const float* __restrict__ b2,
    float* __restrict__ x2b, BF* __restrict__ lnout)
{
    __shared__ __align__(16) BF Bl[128 * LDK128];   // 34816 B
    __shared__ float xs[64][132];                   // [p][c] 33792 B
    __shared__ float gs[128];
    __shared__ float h1[7];
    __shared__ float gl[128];

    const int t = threadIdx.x;
    const int w = t >> 6, lane = t & 63, q = lane >> 4, r16 = lane & 15;
    const int row0 = blockIdx.x * 64;
    const int n = row0 >> 12;
    const int p0 = row0 & 4095;

    {   // stage proj_w (128x128) fully -> [n][k] bf16
        int kk = t >> 1, nn0 = (t & 1) * 64;
        const float* src = Bw + (size_t)kk * CC + nn0;
        #pragma unroll
        for (int u = 0; u < 64; u++) Bl[(nn0 + u) * LDK128 + kk] = f2bf(src[u]);
    }
    {   // stage x tile coalesced: 128 c x 64 p; float4 along p
        #pragma unroll
        for (int it = 0; it < 8; it++) {
            int idx4 = it * 256 + t;         // 2048 float4s
            int p4 = idx4 & 15, c = idx4 >> 4;
            float4 v = *(const float4*)(x + (size_t)(n * CC + c) * HW + p0 + p4 * 4);
            xs[p4 * 4 + 0][c] = v.x; xs[p4 * 4 + 1][c] = v.y;
            xs[p4 * 4 + 2][c] = v.z; xs[p4 * 4 + 3][c] = v.w;
        }
    }
    if (t < 128) gs[t] = part[n * CC + t] * (1.0f / HW);
    __syncthreads();
    if (t < 7) {
        float a = ca1_b[t];
        for (int k = 0; k < 128; k++) a += gs[k] * ca1_w[k * 7 + t];
        h1[t] = fmaxf(a, 0.f);
    }
    __syncthreads();
    if (t < 128) {
        float o = ca2_b[t];
        #pragma unroll
        for (int r = 0; r < 7; r++) o += h1[r] * ca2_w[r * 128 + t];
        gl[t] = 1.0f / (1.0f + expf(-o));
    }

    floatx4 acc[8] = {};
    const BF* arow = A + (size_t)(row0 + w * 16 + r16) * CC;
    #pragma unroll
    for (int ks = 0; ks < 4; ks++) {
        short8 af = *(const short8*)(arow + ks * 32 + q * 8);
        #pragma unroll
        for (int nt = 0; nt < 8; nt++) {
            short8 bf = *(const short8*)(Bl + (nt * 16 + r16) * LDK128 + ks * 32 + q * 8);
            acc[nt] = __builtin_amdgcn_mfma_f32_16x16x32_bf16(af, bf, acc[nt], 0, 0, 0);
        }
    }
    __syncthreads();   // gl ready

    float s1[4] = {0.f, 0.f, 0.f, 0.f}, s2[4] = {0.f, 0.f, 0.f, 0.f};
    #pragma unroll
    for (int nt = 0; nt < 8; nt++) {
        int col = nt * 16 + r16;
        float bv = bias[col];
        float gv = gl[col];
        #pragma unroll
        for (int reg = 0; reg < 4; reg++) {
            int lr = w * 16 + q * 4 + reg;
            int row = row0 + lr;
            float xv = xs[lr][col];
            float tv = tbuf[(size_t)row * CC + col];
            float v = acc[nt][reg] + bv + xv + 0.02f * tv * gv;
            acc[nt][reg] = v;
            s1[reg] += v;
            s2[reg] += v * v;
        }
    }
    #pragma unroll
    for (int reg = 0; reg < 4; reg++) {
        #pragma unroll
        for (int off = 8; off; off >>= 1) {
            s1[reg] += __shfl_xor(s1[reg], off);
            s2[reg] += __shfl_xor(s2[reg], off);
        }
    }
    float mu[4], rr[4];
    #pragma unroll
    for (int reg = 0; reg < 4; reg++) {
        mu[reg] = s1[reg] * (1.0f / CC);
        float var = s2[reg] * (1.0f / CC) - mu[reg] * mu[reg];
        rr[reg] = rsqrtf(var + 1e-5f);
    }
    #pragma unroll
    for (int nt = 0; nt < 8; nt++) {
        int col = nt * 16 + r16;
        float wv = w2[col], bv2 = b2[col];
        #pragma unroll
        for (int reg = 0; reg < 4; reg++) {
            int row = row0 + w * 16 + q * 4 + reg;
            float v = acc[nt][reg];
            x2b[(size_t)row * CC + col] = v;
            lnout[(size_t)row * CC + col] = f2bf((v - mu[reg]) * rr[reg] * wv + bv2);
        }
    }
}

// ---------------- fc2: K=512 GEMM + x2b + coalesced NCHW store --------
// Store tile goes through LDS [col][p]; out rows written as contiguous
// 64-float runs instead of 16KB-strided scalars.
__global__ __launch_bounds__(256) void fc2_kernel(
    const BF* __restrict__ A, const float* __restrict__ B,
    const float* __restrict__ bias, const float* __restrict__ x2b,
    float* __restrict__ out)
{
    __shared__ __align__(16) BF Alds[64][LDK];
    __shared__ __align__(16) BF Blds[64][LDK];   // [n][k]
    __shared__ float st[64][66];                 // [col][p] 16896 B

    const int t    = threadIdx.x;
    const int w    = t >> 6;
    const int lane = t & 63;
    const int q    = lane >> 4;
    const int r16  = lane & 15;
    const int row0 = blockIdx.y * 64;
    const int col0 = blockIdx.x * 64;
    const int n    = row0 >> 12;
    const int p0   = row0 & 4095;

    floatx4 acc[4] = {};
    const int ar = t >> 2;
    const int ak = (t & 3) * 8;
    const int bk = t >> 3;
    const int bn = (t & 7) * 8;

    for (int k0 = 0; k0 < 512; k0 += 32) {
        *(short8*)(&Alds[ar][ak]) =
            *(const short8*)(A + (size_t)(row0 + ar) * 512 + k0 + ak);
        {
            const float* src = B + (size_t)(k0 + bk) * CC + col0 + bn;
            float4 b0 = *(const float4*)(src);
            float4 b1 = *(const float4*)(src + 4);
            Blds[bn + 0][bk] = f2bf(b0.x); Blds[bn + 1][bk] = f2bf(b0.y);
            Blds[bn + 2][bk] = f2bf(b0.z); Blds[bn + 3][bk] = f2bf(b0.w);
            Blds[bn + 4][bk] = f2bf(b1.x); Blds[bn + 5][bk] = f2bf(b1.y);
            Blds[bn + 6][bk] = f2bf(b1.z); Blds[bn + 7][bk] = f2bf(b1.w);
        }
        __syncthreads();
        short8 af = *(const short8*)(&Alds[w * 16 + r16][q * 8]);
        short8 bfm[4];
        #pragma unroll
        for (int nt = 0; nt < 4; nt++)
            bfm[nt] = *(const short8*)(&Blds[nt * 16 + r16][q * 8]);
        #pragma unroll
        for (int nt = 0; nt < 4; nt++)
            acc[nt] = __builtin_amdgcn_mfma_f32_16x16x32_bf16(af, bfm[nt], acc[nt], 0, 0, 0);
        __syncthreads();
    }

    #pragma unroll
    for (int nt = 0; nt < 4; nt++) {
        int col = col0 + nt * 16 + r16;
        float bv = bias[col];
        #pragma unroll
        for (int reg = 0; reg < 4; reg++) {
            int lr = w * 16 + q * 4 + reg;
            int row = row0 + lr;
            st[nt * 16 + r16][lr] = acc[nt][reg] + bv + x2b[(size_t)row * CC + col];
        }
    }
    __syncthreads();
    {   // coalesced store: thread t -> col = t>>2, 16-p chunk = t&3
        int cc = t >> 2, ch = (t & 3) * 16;
        float* dst = out + (size_t)(n * CC + col0 + cc) * HW + p0 + ch;
        #pragma unroll
        for (int u = 0; u < 4; u++) {
            float4 v;
            v.x = st[cc][ch + u * 4 + 0];
            v.y = st[cc][ch + u * 4 + 1];
            v.z = st[cc][ch + u * 4 + 2];
            v.w = st[cc][ch + u * 4 + 3];
            *(float4*)(dst + u * 4) = v;
        }
    }
}

extern "C" void kernel_launch(void* const* d_in, const int* in_sizes, int n_in,
                              void* d_out, int out_size, void* d_ws, size_t ws_size,
                              hipStream_t stream)
{
    const float* x       = (const float*)d_in[0];
    const float* ln1_w   = (const float*)d_in[1];
    const float* ln1_b   = (const float*)d_in[2];
    const float* ln2_w   = (const float*)d_in[3];
    const float* ln2_b   = (const float*)d_in[4];
    const float* qkv_w   = (const float*)d_in[5];
    const float* qkv_b   = (const float*)d_in[6];
    const float* proj_w  = (const float*)d_in[7];
    const float* proj_b  = (const float*)d_in[8];
    const float* rpb     = (const float*)d_in[9];
    const float* conv1_w = (const float*)d_in[10];
    const float* conv1_b = (const float*)d_in[11];
    const float* conv2_w = (const float*)d_in[12];
    const float* conv2_b = (const float*)d_in[13];
    const float* ca1_w   = (const float*)d_in[14];
    const float* ca1_b   = (const float*)d_in[15];
    const float* ca2_w   = (const float*)d_in[16];
    const float* ca2_b   = (const float*)d_in[17];
    const float* fc1_w   = (const float*)d_in[18];
    const float* fc1_b   = (const float*)d_in[19];
    const float* fc2_w   = (const float*)d_in[20];
    const float* fc2_b   = (const float*)d_in[21];
    float* out = (float*)d_out;

    // workspace (bytes). hbuf_bf overlays xn_bf+qkv_bf (both dead by fc1).
    char* ws = (char*)d_ws;
    BF*    xn_bf   = (BF*)(ws);                  // M*128*2 = 4 MB
    BF*    qkv_bf  = (BF*)(ws + 4194304);        // M*384*2 = 12 MB
    BF*    hbuf_bf = (BF*)(ws);                  // M*512*2 = 16 MB (overlay)
    float* t       = (float*)(ws + 16777216);    // M*128*4 = 8 MB
    float* x2b     = (float*)(ws + 25165824);    // M*128*4 = 8 MB
    BF*    na_bf   = (BF*)(ws + 33554432);       // M*128*2 = 4 MB
    BF*    ln2_bf  = (BF*)(ws + 37748736);       // M*128*2 = 4 MB
    float* part    = (float*)(ws + 41943040);    // 2 KB

    // 1. LN1 transpose-tile (coalesced NCHW read; zeroes part)
    ln1t_kernel<<<512, 256, 0, stream>>>(x, ln1_w, ln1_b, xn_bf, part);
    // 2. qkv GEMM + conv-MLP (+column sums), one launch
    phase2<<<1792, 256, 0, stream>>>(xn_bf, qkv_w, qkv_b, qkv_bf,
                                     conv1_w, conv1_b, conv2_w, conv2_b, t, part);
    // 3. neighborhood attention
    na_tile_kernel<<<1024, 512, 0, stream>>>(qkv_bf, rpb, (unsigned*)na_bf);
    // 4. CA gate + proj + x2 residual + LN2 (coalesced x staging)
    projx2ln2g<<<256, 256, 0, stream>>>(na_bf, proj_w, proj_b, x, t, part,
                                        ca1_w, ca1_b, ca2_w, ca2_b,
                                        ln2_w, ln2_b, x2b, ln2_bf);
    // 5. fc1: (M,128)@(128,512)+gelu -> bf16 (overlays xn/qkv)
    gemm_k128<1><<<dim3(8, 256), 256, 0, stream>>>(ln2_bf, fc1_w, fc1_b, hbuf_bf, 512);
    // 6. fc2: K=512 + x2b, coalesced NHWC->NCHW store
    fc2_kernel<<<dim3(2, 256), 256, 0, stream>>>(hbuf_bf, fc2_w, fc2_b, x2b, out);
}

// Round 10
// 193.302 us; speedup vs baseline: 1.1762x; 1.0627x over previous
//
#include <hip/hip_runtime.h>
#include <hip/hip_bf16.h>
#include <math.h>

#define NB 4
#define CC 128
#define HH 64
#define WW 64
#define HEADS 4
#define KS 7
#define DD 32
#define HW 4096
#define MTOT 16384   // NB*HW

typedef unsigned short BF;
typedef short short8 __attribute__((ext_vector_type(8)));
typedef float floatx4 __attribute__((ext_vector_type(4)));

__device__ __forceinline__ float gelu_f(float x) {
    return 0.5f * x * (1.0f + erff(x * 0.70710678118654752440f));
}

__device__ __forceinline__ BF f2bf(float f) {
    union { float f; unsigned u; } a; a.f = f;
    unsigned u = a.u;
    unsigned r = u + 0x7FFFu + ((u >> 16) & 1u);   // RNE
    return (BF)(r >> 16);
}

__device__ __forceinline__ float bf2f(BF v) {
    return __uint_as_float(((unsigned)v) << 16);
}

#define LDK 40      // padded LDS row, K=32 tiles (bf16)
#define LDK128 136  // padded LDS row, K=128 tiles (bf16)

// ---------------- LN1 transpose-tile: NCHW -> bf16 NHWC rows ----------
__global__ __launch_bounds__(256) void ln1t_kernel(
    const float* __restrict__ x, const float* __restrict__ w,
    const float* __restrict__ b, BF* __restrict__ out,
    float* __restrict__ part)
{
    __shared__ float xt[128][33];
    __shared__ float mus[32], rss[32];
    const int blk = blockIdx.x;          // 0..511
    const int n  = blk >> 7;
    const int p0 = (blk & 127) * 32;
    const int t  = threadIdx.x;
    if (blk < 4 && t < 128) part[blk * CC + t] = 0.f;   // zero CA partials

    {
        int pp = t & 31, c8 = t >> 5;
        #pragma unroll 4
        for (int it = 0; it < 16; it++) {
            int c = it * 8 + c8;
            xt[c][pp] = x[(size_t)(n * CC + c) * HW + p0 + pp];
        }
    }
    __syncthreads();
    {
        int pp2 = t >> 3, cb = t & 7;
        float s = 0.f;
        #pragma unroll
        for (int u = 0; u < 16; u++) s += xt[cb + u * 8][pp2];
        s += __shfl_xor(s, 1); s += __shfl_xor(s, 2); s += __shfl_xor(s, 4);
        float mu = s * (1.0f / CC);
        float v = 0.f;
        #pragma unroll
        for (int u = 0; u < 16; u++) { float d = xt[cb + u * 8][pp2] - mu; v += d * d; }
        v += __shfl_xor(v, 1); v += __shfl_xor(v, 2); v += __shfl_xor(v, 4);
        if (cb == 0) { mus[pp2] = mu; rss[pp2] = rsqrtf(v * (1.0f / CC) + 1e-5f); }
    }
    __syncthreads();
    {
        #pragma unroll
        for (int it = 0; it < 2; it++) {
            int pp2 = (t >> 4) + it * 16;
            int c0  = (t & 15) * 8;
            float mu = mus[pp2], rs = rss[pp2];
            int m = n * HW + p0 + pp2;
            short8 o;
            #pragma unroll
            for (int u = 0; u < 8; u++)
                o[u] = (short)f2bf((xt[c0 + u][pp2] - mu) * rs * w[c0 + u] + b[c0 + u]);
            *(short8*)(out + (size_t)m * CC + c0) = o;
        }
    }
}

// ---------------- K=128 barrier-lean GEMM body (LDS-staged B) ---------
template<int ACT>
__device__ __forceinline__ void k128_body(
    const BF* __restrict__ A, const float* __restrict__ B,
    const float* __restrict__ bias, BF* __restrict__ Cout,
    int N, int row0, int col0, BF* Bl /* [64][LDK128] */)
{
    const int t = threadIdx.x;
    const int w = t >> 6, lane = t & 63, q = lane >> 4, r16 = lane & 15;
    {   // stage B slice 128x64 -> [n][k]
        int kk = t >> 1, nn0 = (t & 1) * 32;
        const float* src = B + (size_t)kk * N + col0 + nn0;
        #pragma unroll
        for (int u = 0; u < 32; u++) Bl[(nn0 + u) * LDK128 + kk] = f2bf(src[u]);
    }
    __syncthreads();
    floatx4 acc[4] = {};
    const BF* arow = A + (size_t)(row0 + w * 16 + r16) * CC;
    #pragma unroll
    for (int ks = 0; ks < 4; ks++) {
        short8 af = *(const short8*)(arow + ks * 32 + q * 8);
        #pragma unroll
        for (int nt = 0; nt < 4; nt++) {
            short8 bf = *(const short8*)(Bl + (nt * 16 + r16) * LDK128 + ks * 32 + q * 8);
            acc[nt] = __builtin_amdgcn_mfma_f32_16x16x32_bf16(af, bf, acc[nt], 0, 0, 0);
        }
    }
    #pragma unroll
    for (int nt = 0; nt < 4; nt++) {
        int col = col0 + nt * 16 + r16;
        float bv = bias[col];
        #pragma unroll
        for (int reg = 0; reg < 4; reg++) {
            int row = row0 + w * 16 + q * 4 + reg;
            float v = acc[nt][reg] + bv;
            if (ACT == 1) v = gelu_f(v);
            Cout[(size_t)row * N + col] = f2bf(v);
        }
    }
}

// ---------------- phase2: qkv GEMM blocks + conv-MLP blocks -----------
// conv t output now bf16 (column sums still from f32 pre-round values)
__global__ __launch_bounds__(256) void phase2(
    const BF* __restrict__ xn, const float* __restrict__ qkv_w,
    const float* __restrict__ qkv_b, BF* __restrict__ qkv_out,
    const float* __restrict__ w1, const float* __restrict__ b1,
    const float* __restrict__ w2, const float* __restrict__ b2,
    BF* __restrict__ tout, float* __restrict__ part)
{
    __shared__ __align__(16) char smem[26624];
    const int bid = blockIdx.x;
    const int t = threadIdx.x;
    const int w = t >> 6, lane = t & 63, q = lane >> 4, r16 = lane & 15;

    if (bid < 1536) {
        int col0 = (bid % 6) * 64;
        int row0 = (bid / 6) * 64;
        k128_body<0>(xn, qkv_w, qkv_b, qkv_out, 384, row0, col0, (BF*)smem);
        return;
    }
    // ---- conv branch ----
    BF*    W1l = (BF*)smem;                  // [32][LDK128]  8704 B
    BF*    W2l = (BF*)(smem + 8704);         // [128][LDK]   10240 B
    BF*    Hl  = (BF*)(smem + 18944);        // [64][LDK]     5120 B
    float* red = (float*)(smem + 24064);     // [4][128]      2048 B
    const int row0 = (bid - 1536) * 64;
    {
        int kk = t >> 1, nn = (t & 1) * 16;
        const float* src = w1 + (size_t)kk * 32 + nn;
        #pragma unroll
        for (int u = 0; u < 16; u++) W1l[(nn + u) * LDK128 + kk] = f2bf(src[u]);
    }
    {
        int kk = t >> 3, n0 = (t & 7) * 16;
        const float* src = w2 + (size_t)kk * 128 + n0;
        #pragma unroll
        for (int u = 0; u < 16; u++) W2l[(n0 + u) * LDK + kk] = f2bf(src[u]);
    }
    __syncthreads();
    floatx4 a1[2] = {};
    const BF* arow = xn + (size_t)(row0 + w * 16 + r16) * CC;
    #pragma unroll
    for (int ks = 0; ks < 4; ks++) {
        short8 af = *(const short8*)(arow + ks * 32 + q * 8);
        #pragma unroll
        for (int nt = 0; nt < 2; nt++) {
            short8 bf = *(const short8*)(W1l + (nt * 16 + r16) * LDK128 + ks * 32 + q * 8);
            a1[nt] = __builtin_amdgcn_mfma_f32_16x16x32_bf16(af, bf, a1[nt], 0, 0, 0);
        }
    }
    #pragma unroll
    for (int nt = 0; nt < 2; nt++) {
        int col = nt * 16 + r16;
        float bv = b1[col];
        #pragma unroll
        for (int reg = 0; reg < 4; reg++)
            Hl[(w * 16 + q * 4 + reg) * LDK + col] = f2bf(gelu_f(a1[nt][reg] + bv));
    }
    __syncthreads();
    floatx4 a2[8] = {};
    short8 af2 = *(const short8*)(Hl + (w * 16 + r16) * LDK + q * 8);
    #pragma unroll
    for (int nt = 0; nt < 8; nt++) {
        short8 bf = *(const short8*)(W2l + (nt * 16 + r16) * LDK + q * 8);
        a2[nt] = __builtin_amdgcn_mfma_f32_16x16x32_bf16(af2, bf, a2[nt], 0, 0, 0);
    }
    #pragma unroll
    for (int nt = 0; nt < 8; nt++) {
        int col = nt * 16 + r16;
        float bv = b2[col];
        float s = 0.f;
        #pragma unroll
        for (int reg = 0; reg < 4; reg++) {
            int row = row0 + w * 16 + q * 4 + reg;
            float v = a2[nt][reg] + bv;
            tout[(size_t)row * CC + col] = f2bf(v);
            s += v;
        }
        s += __shfl_xor(s, 16);
        s += __shfl_xor(s, 32);
        if (lane < 16) red[w * 128 + col] = s;
    }
    __syncthreads();
    if (t < 128) {
        float cs = red[t] + red[128 + t] + red[256 + t] + red[384 + t];
        atomicAdd(&part[(row0 >> 12) * CC + t], cs);
    }
}

// ---------------- standalone K=128 GEMM (fc1) -------------------------
template<int ACT>
__global__ __launch_bounds__(256) void gemm_k128(
    const BF* __restrict__ A, const float* __restrict__ B,
    const float* __restrict__ bias, BF* __restrict__ Cout, int N)
{
    __shared__ __align__(16) BF Bl[64 * LDK128];
    k128_body<ACT>(A, B, bias, Cout, N, blockIdx.y * 64, blockIdx.x * 64, Bl);
}

// ---------------- MFMA neighborhood attention -------------------------
// block = 8x8 query tile x 1 head; 256 threads = 4 waves x 16 queries.
// Key grid 14x16 (key = kr*16+kc -> n-tile index == kr, kc == lane&15):
// mask/bias geometry is per-(tile,reg) arithmetic + rpb LDS gather.
// Score: 14 MFMAs (Q a-frag, K[key][d] b-frag). Softmax in C-layout regs
// (row reduce = 4 shuffles over lane&15). P -> LDS (A-layout) -> PV:
// 7 k-steps x 2 d-tiles vs Vt[d][key]. All bf16 in, fp32 accum.
__global__ __launch_bounds__(256) void na_mfma_kernel(
    const BF* __restrict__ qkv, const float* __restrict__ rpb,
    BF* __restrict__ outp)
{
    __shared__ __align__(16) BF Kt[224][40];      // [key][d] 17920 B
    __shared__ __align__(16) BF Vt[32][232];      // [d][key] 14848 B
    __shared__ __align__(16) BF Qb[64][40];       // [q][d]    5120 B
    __shared__ __align__(16) BF Pl[4][16][232];   // per-wave P 29696 B
    __shared__ float rb[169];

    const int b = blockIdx.x;
    const int h = b & 3;
    const int tile = b >> 2;
    const int n = tile >> 6;
    const int ti = (tile >> 3) & 7, tj = tile & 7;
    const int t = threadIdx.x;
    const int w = t >> 6, lane = t & 63, quad = lane >> 4, r16 = lane & 15;
    const int i0 = ti * 8, j0 = tj * 8;
    const int wi0 = max(i0 - 3, 0), wj0 = max(j0 - 3, 0);
    const int R  = min(wi0 + 13, 63) - wi0 + 1;
    const int Rj = min(wj0 + 13, 63) - wj0 + 1;

    // ---- stage K [key][d] (zero-pad invalid keys) ----
    for (int idx = t; idx < 896; idx += 256) {
        int key = idx >> 2, ch = idx & 3;
        int kr = key >> 4, kc = key & 15;
        uint4 v = {0u, 0u, 0u, 0u};
        if (kr < R && kc < Rj) {
            size_t pix = (size_t)((n * HH + wi0 + kr) * WW + wj0 + kc);
            v = *(const uint4*)(qkv + pix * 384 + 128 + h * DD + ch * 8);
        }
        *(uint4*)&Kt[key][ch * 8] = v;
    }
    // ---- stage V transposed [d][key] (zero-pad) ----
    for (int idx = t; idx < 896; idx += 256) {
        int key = idx >> 2, ch = idx & 3;
        int kr = key >> 4, kc = key & 15;
        if (kr < R && kc < Rj) {
            size_t pix = (size_t)((n * HH + wi0 + kr) * WW + wj0 + kc);
            uint4 v = *(const uint4*)(qkv + pix * 384 + 256 + h * DD + ch * 8);
            const BF* pv = (const BF*)&v;
            #pragma unroll
            for (int u = 0; u < 8; u++) Vt[ch * 8 + u][key] = pv[u];
        } else {
            #pragma unroll
            for (int u = 0; u < 8; u++) Vt[ch * 8 + u][key] = 0;
        }
    }
    // ---- stage Q (one uint4 per thread: 64 q x 4 chunks) ----
    {
        int q = t >> 2, ch = t & 3;
        size_t mq = (size_t)((n * HH + i0 + (q >> 3)) * WW + j0 + (q & 7));
        *(uint4*)&Qb[q][ch * 8] = *(const uint4*)(qkv + mq * 384 + h * DD + ch * 8);
    }
    if (t < 169) rb[t] = rpb[h * 169 + t];
    __syncthreads();

    // ---- per-reg query geometry ----
    int oi[4], cok[4], bj0[4], ai_[4];
    #pragma unroll
    for (int reg = 0; reg < 4; reg++) {
        int q = w * 16 + quad * 4 + reg;
        int i = i0 + (q >> 3), j = j0 + (q & 7);
        int ni = min(max(i - 3, 0), HH - KS), nj = min(max(j - 3, 0), WW - KS);
        oi[reg]  = ni - wi0;
        ai_[reg] = ni - i + 6;
        int dc = r16 - (nj - wj0);
        cok[reg] = ((unsigned)dc < 7u) ? 1 : 0;
        bj0[reg] = min(max(dc + (nj - j + 6), 0), 12);
    }

    // ---- scores: 14 MFMAs ----
    short8 aq = *(const short8*)&Qb[w * 16 + r16][quad * 8];
    floatx4 S[14];
    #pragma unroll
    for (int nt = 0; nt < 14; nt++) {
        floatx4 z = {0.f, 0.f, 0.f, 0.f};
        short8 bk = *(const short8*)&Kt[nt * 16 + r16][quad * 8];
        S[nt] = __builtin_amdgcn_mfma_f32_16x16x32_bf16(aq, bk, z, 0, 0, 0);
    }
    // ---- mask + rpb bias ----
    const float scale = 0.17677669529663688110f;
    #pragma unroll
    for (int nt = 0; nt < 14; nt++) {
        #pragma unroll
        for (int reg = 0; reg < 4; reg++) {
            int dr = nt - oi[reg];
            bool ok = ((unsigned)dr < 7u) && cok[reg];
            int bi = min(max(dr + ai_[reg], 0), 12);
            float bias = rb[bi * 13 + bj0[reg]];
            S[nt][reg] = ok ? fmaf(S[nt][reg], scale, bias) : -1e30f;
        }
    }
    // ---- softmax per row (in-lane over 14 tiles + 4 shuffles) ----
    float rinv[4];
    #pragma unroll
    for (int reg = 0; reg < 4; reg++) {
        float m = S[0][reg];
        #pragma unroll
        for (int nt = 1; nt < 14; nt++) m = fmaxf(m, S[nt][reg]);
        m = fmaxf(m, __shfl_xor(m, 1));
        m = fmaxf(m, __shfl_xor(m, 2));
        m = fmaxf(m, __shfl_xor(m, 4));
        m = fmaxf(m, __shfl_xor(m, 8));
        float s = 0.f;
        #pragma unroll
        for (int nt = 0; nt < 14; nt++) {
            float e = __expf(S[nt][reg] - m);
            S[nt][reg] = e;
            s += e;
        }
        s += __shfl_xor(s, 1);
        s += __shfl_xor(s, 2);
        s += __shfl_xor(s, 4);
        s += __shfl_xor(s, 8);
        rinv[reg] = 1.0f / s;
    }
    // ---- P -> LDS in A-layout (same-wave region, no barrier) ----
    #pragma unroll
    for (int nt = 0; nt < 14; nt++)
        #pragma unroll
        for (int reg = 0; reg < 4; reg++)
            Pl[w][quad * 4 + reg][nt * 16 + r16] = f2bf(S[nt][reg] * rinv[reg]);

    // ---- PV: 7 k-steps x 2 d-tiles ----
    floatx4 O0 = {0.f, 0.f, 0.f, 0.f}, O1 = {0.f, 0.f, 0.f, 0.f};
    #pragma unroll
    for (int ks = 0; ks < 7; ks++) {
        short8 ap = *(const short8*)&Pl[w][r16][ks * 32 + quad * 8];
        short8 b0 = *(const short8*)&Vt[r16][ks * 32 + quad * 8];
        short8 b1 = *(const short8*)&Vt[16 + r16][ks * 32 + quad * 8];
        O0 = __builtin_amdgcn_mfma_f32_16x16x32_bf16(ap, b0, O0, 0, 0, 0);
        O1 = __builtin_amdgcn_mfma_f32_16x16x32_bf16(ap, b1, O1, 0, 0, 0);
    }
    #pragma unroll
    for (int reg = 0; reg < 4; reg++) {
        int q = w * 16 + quad * 4 + reg;
        size_t m = (size_t)((n * HH + i0 + (q >> 3)) * WW + j0 + (q & 7));
        outp[m * CC + h * DD + r16]      = f2bf(O0[reg]);
        outp[m * CC + h * DD + 16 + r16] = f2bf(O1[reg]);
    }
}

// ---------------- fused CA-gate + proj GEMM + x2 + LN2 ----------------
__global__ __launch_bounds__(256) void projx2ln2g(
    const BF* __restrict__ A, const float* __restrict__ Bw,
    const float* __restrict__ bias, const float* __restrict__ x,
    const BF* __restrict__ tbuf, const float* __restrict__ part,
    const float* __restrict__ ca1_w, const float* __restrict__ ca1_b,
    const float* __restrict__ ca2_w, const float* __restrict__ ca2_b,
    const float* __restrict__ w2, const float* __restrict__ b2,
    float* __restrict__ x2b, BF* __restrict__ lnout)
{
    __shared__ __align__(16) BF Bl[128 * LDK128];   // 34816 B
    __shared__ float xs[64][132];                   // [p][c] 33792 B
    __shared__ float gs[128];
    __shared__ float h1[7];
    __shared__ float gl[128];

    const int t = threadIdx.x;
    const int w = t >> 6, lane = t & 63, q = lane >> 4, r16 = lane & 15;
    const int row0 = blockIdx.x * 64;
    const int n = row0 >> 12;
    const int p0 = row0 & 4095;

    {   // stage proj_w (128x128) fully -> [n][k] bf16
        int kk = t >> 1, nn0 = (t & 1) * 64;
        const float* src = Bw + (size_t)kk * CC + nn0;
        #pragma unroll
        for (int u = 0; u < 64; u++) Bl[(nn0 + u) * LDK128 + kk] = f2bf(src[u]);
    }
    {   // stage x tile coalesced: 128 c x 64 p; float4 along p
        #pragma unroll
        for (int it = 0; it < 8; it++) {
            int idx4 = it * 256 + t;
            int p4 = idx4 & 15, c = idx4 >> 4;
            float4 v = *(const float4*)(x + (size_t)(n * CC + c) * HW + p0 + p4 * 4);
            xs[p4 * 4 + 0][c] = v.x; xs[p4 * 4 + 1][c] = v.y;
            xs[p4 * 4 + 2][c] = v.z; xs[p4 * 4 + 3][c] = v.w;
        }
    }
    if (t < 128) gs[t] = part[n * CC + t] * (1.0f / HW);
    __syncthreads();
    if (t < 7) {
        float a = ca1_b[t];
        for (int k = 0; k < 128; k++) a += gs[k] * ca1_w[k * 7 + t];
        h1[t] = fmaxf(a, 0.f);
    }
    __syncthreads();
    if (t < 128) {
        float o = ca2_b[t];
        #pragma unroll
        for (int r = 0; r < 7; r++) o += h1[r] * ca2_w[r * 128 + t];
        gl[t] = 1.0f / (1.0f + expf(-o));
    }

    floatx4 acc[8] = {};
    const BF* arow = A + (size_t)(row0 + w * 16 + r16) * CC;
    #pragma unroll
    for (int ks = 0; ks < 4; ks++) {
        short8 af = *(const short8*)(arow + ks * 32 + q * 8);
        #pragma unroll
        for (int nt = 0; nt < 8; nt++) {
            short8 bf = *(const short8*)(Bl + (nt * 16 + r16) * LDK128 + ks * 32 + q * 8);
            acc[nt] = __builtin_amdgcn_mfma_f32_16x16x32_bf16(af, bf, acc[nt], 0, 0, 0);
        }
    }
    __syncthreads();   // gl ready

    float s1[4] = {0.f, 0.f, 0.f, 0.f}, s2[4] = {0.f, 0.f, 0.f, 0.f};
    #pragma unroll
    for (int nt = 0; nt < 8; nt++) {
        int col = nt * 16 + r16;
        float bv = bias[col];
        float gv = gl[col];
        #pragma unroll
        for (int reg = 0; reg < 4; reg++) {
            int lr = w * 16 + q * 4 + reg;
            int row = row0 + lr;
            float xv = xs[lr][col];
            float tv = bf2f(tbuf[(size_t)row * CC + col]);
            float v = acc[nt][reg] + bv + xv + 0.02f * tv * gv;
            acc[nt][reg] = v;
            s1[reg] += v;
            s2[reg] += v * v;
        }
    }
    #pragma unroll
    for (int reg = 0; reg < 4; reg++) {
        #pragma unroll
        for (int off = 8; off; off >>= 1) {
            s1[reg] += __shfl_xor(s1[reg], off);
            s2[reg] += __shfl_xor(s2[reg], off);
        }
    }
    float mu[4], rr[4];
    #pragma unroll
    for (int reg = 0; reg < 4; reg++) {
        mu[reg] = s1[reg] * (1.0f / CC);
        float var = s2[reg] * (1.0f / CC) - mu[reg] * mu[reg];
        rr[reg] = rsqrtf(var + 1e-5f);
    }
    #pragma unroll
    for (int nt = 0; nt < 8; nt++) {
        int col = nt * 16 + r16;
        float wv = w2[col], bv2 = b2[col];
        #pragma unroll
        for (int reg = 0; reg < 4; reg++) {
            int row = row0 + w * 16 + q * 4 + reg;
            float v = acc[nt][reg];
            x2b[(size_t)row * CC + col] = v;
            lnout[(size_t)row * CC + col] = f2bf((v - mu[reg]) * rr[reg] * wv + bv2);
        }
    }
}

// ---------------- fc2: K=512 GEMM + x2b + coalesced NCHW store --------
__global__ __launch_bounds__(256) void fc2_kernel(
    const BF* __restrict__ A, const float* __restrict__ B,
    const float* __restrict__ bias, const float* __restrict__ x2b,
    float* __restrict__ out)
{
    __shared__ __align__(16) BF Alds[64][LDK];
    __shared__ __align__(16) BF Blds[64][LDK];   // [n][k]
    __shared__ float st[64][66];                 // [col][p] 16896 B

    const int t    = threadIdx.x;
    const int w    = t >> 6;
    const int lane = t & 63;
    const int q    = lane >> 4;
    const int r16  = lane & 15;
    const int row0 = blockIdx.y * 64;
    const int col0 = blockIdx.x * 64;
    const int n    = row0 >> 12;
    const int p0   = row0 & 4095;

    floatx4 acc[4] = {};
    const int ar = t >> 2;
    const int ak = (t & 3) * 8;
    const int bk = t >> 3;
    const int bn = (t & 7) * 8;

    for (int k0 = 0; k0 < 512; k0 += 32) {
        *(short8*)(&Alds[ar][ak]) =
            *(const short8*)(A + (size_t)(row0 + ar) * 512 + k0 + ak);
        {
            const float* src = B + (size_t)(k0 + bk) * CC + col0 + bn;
            float4 b0 = *(const float4*)(src);
            float4 b1 = *(const float4*)(src + 4);
            Blds[bn + 0][bk] = f2bf(b0.x); Blds[bn + 1][bk] = f2bf(b0.y);
            Blds[bn + 2][bk] = f2bf(b0.z); Blds[bn + 3][bk] = f2bf(b0.w);
            Blds[bn + 4][bk] = f2bf(b1.x); Blds[bn + 5][bk] = f2bf(b1.y);
            Blds[bn + 6][bk] = f2bf(b1.z); Blds[bn + 7][bk] = f2bf(b1.w);
        }
        __syncthreads();
        short8 af = *(const short8*)(&Alds[w * 16 + r16][q * 8]);
        short8 bfm[4];
        #pragma unroll
        for (int nt = 0; nt < 4; nt++)
            bfm[nt] = *(const short8*)(&Blds[nt * 16 + r16][q * 8]);
        #pragma unroll
        for (int nt = 0; nt < 4; nt++)
            acc[nt] = __builtin_amdgcn_mfma_f32_16x16x32_bf16(af, bfm[nt], acc[nt], 0, 0, 0);
        __syncthreads();
    }

    #pragma unroll
    for (int nt = 0; nt < 4; nt++) {
        int col = col0 + nt * 16 + r16;
        float bv = bias[col];
        #pragma unroll
        for (int reg = 0; reg < 4; reg++) {
            int lr = w * 16 + q * 4 + reg;
            int row = row0 + lr;
            st[nt * 16 + r16][lr] = acc[nt][reg] + bv + x2b[(size_t)row * CC + col];
        }
    }
    __syncthreads();
    {
        int cc = t >> 2, ch = (t & 3) * 16;
        float* dst = out + (size_t)(n * CC + col0 + cc) * HW + p0 + ch;
        #pragma unroll
        for (int u = 0; u < 4; u++) {
            float4 v;
            v.x = st[cc][ch + u * 4 + 0];
            v.y = st[cc][ch + u * 4 + 1];
            v.z = st[cc][ch + u * 4 + 2];
            v.w = st[cc][ch + u * 4 + 3];
            *(float4*)(dst + u * 4) = v;
        }
    }
}

extern "C" void kernel_launch(void* const* d_in, const int* in_sizes, int n_in,
                              void* d_out, int out_size, void* d_ws, size_t ws_size,
                              hipStream_t stream)
{
    const float* x       = (const float*)d_in[0];
    const float* ln1_w   = (const float*)d_in[1];
    const float* ln1_b   = (const float*)d_in[2];
    const float* ln2_w   = (const float*)d_in[3];
    const float* ln2_b   = (const float*)d_in[4];
    const float* qkv_w   = (const float*)d_in[5];
    const float* qkv_b   = (const float*)d_in[6];
    const float* proj_w  = (const float*)d_in[7];
    const float* proj_b  = (const float*)d_in[8];
    const float* rpb     = (const float*)d_in[9];
    const float* conv1_w = (const float*)d_in[10];
    const float* conv1_b = (const float*)d_in[11];
    const float* conv2_w = (const float*)d_in[12];
    const float* conv2_b = (const float*)d_in[13];
    const float* ca1_w   = (const float*)d_in[14];
    const float* ca1_b   = (const float*)d_in[15];
    const float* ca2_w   = (const float*)d_in[16];
    const float* ca2_b   = (const float*)d_in[17];
    const float* fc1_w   = (const float*)d_in[18];
    const float* fc1_b   = (const float*)d_in[19];
    const float* fc2_w   = (const float*)d_in[20];
    const float* fc2_b   = (const float*)d_in[21];
    float* out = (float*)d_out;

    // workspace (bytes). hbuf_bf overlays xn_bf+qkv_bf (both dead by fc1).
    char* ws = (char*)d_ws;
    BF*    xn_bf   = (BF*)(ws);                  // M*128*2 = 4 MB
    BF*    qkv_bf  = (BF*)(ws + 4194304);        // M*384*2 = 12 MB
    BF*    hbuf_bf = (BF*)(ws);                  // M*512*2 = 16 MB (overlay)
    BF*    t_bf    = (BF*)(ws + 16777216);       // M*128*2 = 4 MB
    float* x2b     = (float*)(ws + 25165824);    // M*128*4 = 8 MB
    BF*    na_bf   = (BF*)(ws + 33554432);       // M*128*2 = 4 MB
    BF*    ln2_bf  = (BF*)(ws + 37748736);       // M*128*2 = 4 MB
    float* part    = (float*)(ws + 41943040);    // 2 KB

    // 1. LN1 transpose-tile (coalesced NCHW read; zeroes part)
    ln1t_kernel<<<512, 256, 0, stream>>>(x, ln1_w, ln1_b, xn_bf, part);
    // 2. qkv GEMM + conv-MLP (+column sums), one launch
    phase2<<<1792, 256, 0, stream>>>(xn_bf, qkv_w, qkv_b, qkv_bf,
                                     conv1_w, conv1_b, conv2_w, conv2_b, t_bf, part);
    // 3. MFMA neighborhood attention
    na_mfma_kernel<<<1024, 256, 0, stream>>>(qkv_bf, rpb, na_bf);
    // 4. CA gate + proj + x2 residual + LN2 (coalesced x staging)
    projx2ln2g<<<256, 256, 0, stream>>>(na_bf, proj_w, proj_b, x, t_bf, part,
                                        ca1_w, ca1_b, ca2_w, ca2_b,
                                        ln2_w, ln2_b, x2b, ln2_bf);
    // 5. fc1: (M,128)@(128,512)+gelu -> bf16 (overlays xn/qkv)
    gemm_k128<1><<<dim3(8, 256), 256, 0, stream>>>(ln2_bf, fc1_w, fc1_b, hbuf_bf, 512);
    // 6. fc2: K=512 + x2b, coalesced NHWC->NCHW store
    fc2_kernel<<<dim3(2, 256), 256, 0, stream>>>(hbuf_bf, fc2_w, fc2_b, x2b, out);
}

// Round 11
// 174.621 us; speedup vs baseline: 1.3021x; 1.1070x over previous
//
#include <hip/hip_runtime.h>
#include <hip/hip_bf16.h>
#include <math.h>

#define NB 4
#define CC 128
#define HH 64
#define WW 64
#define HEADS 4
#define KS 7
#define DD 32
#define HW 4096
#define MTOT 16384   // NB*HW

typedef unsigned short BF;
typedef short short8 __attribute__((ext_vector_type(8)));
typedef float floatx4 __attribute__((ext_vector_type(4)));

__device__ __forceinline__ float gelu_f(float x) {
    return 0.5f * x * (1.0f + erff(x * 0.70710678118654752440f));
}

__device__ __forceinline__ BF f2bf(float f) {
    union { float f; unsigned u; } a; a.f = f;
    unsigned u = a.u;
    unsigned r = u + 0x7FFFu + ((u >> 16) & 1u);   // RNE
    return (BF)(r >> 16);
}

__device__ __forceinline__ float bf2f(BF v) {
    return __uint_as_float(((unsigned)v) << 16);
}

#define LDK 40      // padded LDS row, K=32 tiles (bf16)
#define LDK128 136  // padded LDS row, K=128 tiles (bf16)

// ---------------- LN1 transpose-tile + one-time weight prep -----------
// blocks [0,512): LN1 NCHW -> bf16 NHWC rows
// blocks [512,640): all 6 weights f32 (K,N) -> bf16 (N,K) once
__global__ __launch_bounds__(256) void ln1t_kernel(
    const float* __restrict__ x, const float* __restrict__ w,
    const float* __restrict__ b, BF* __restrict__ out,
    float* __restrict__ part,
    const float* __restrict__ qkv_w, const float* __restrict__ conv1_w,
    const float* __restrict__ conv2_w, const float* __restrict__ proj_w,
    const float* __restrict__ fc1_w, const float* __restrict__ fc2_w,
    BF* __restrict__ qkvT, BF* __restrict__ c1T, BF* __restrict__ c2T,
    BF* __restrict__ projT, BF* __restrict__ fc1T, BF* __restrict__ fc2T)
{
    const int blk = blockIdx.x;
    const int t  = threadIdx.x;

    if (blk >= 512) {   // ---- weight prep (one-time, 204800 elems) ----
        for (int idx = (blk - 512) * 256 + t; idx < 204800; idx += 32768) {
            if (idx < 49152) {                    // qkvT [384][128]
                int l = idx, n = l >> 7, k = l & 127;
                qkvT[l] = f2bf(qkv_w[k * 384 + n]);
            } else if (idx < 53248) {             // c1T [32][128]
                int l = idx - 49152, n = l >> 7, k = l & 127;
                c1T[l] = f2bf(conv1_w[k * 32 + n]);
            } else if (idx < 57344) {             // c2T [128][32]
                int l = idx - 53248, n = l >> 5, k = l & 31;
                c2T[l] = f2bf(conv2_w[k * 128 + n]);
            } else if (idx < 73728) {             // projT [128][128]
                int l = idx - 57344, n = l >> 7, k = l & 127;
                projT[l] = f2bf(proj_w[k * 128 + n]);
            } else if (idx < 139264) {            // fc1T [512][128]
                int l = idx - 73728, n = l >> 7, k = l & 127;
                fc1T[l] = f2bf(fc1_w[k * 512 + n]);
            } else {                              // fc2T [128][512]
                int l = idx - 139264, n = l >> 9, k = l & 511;
                fc2T[l] = f2bf(fc2_w[k * 128 + n]);
            }
        }
        return;
    }

    __shared__ float xt[128][33];
    __shared__ float mus[32], rss[32];
    const int n  = blk >> 7;
    const int p0 = (blk & 127) * 32;
    if (blk < 4 && t < 128) part[blk * CC + t] = 0.f;   // zero CA partials

    {
        int pp = t & 31, c8 = t >> 5;
        #pragma unroll 4
        for (int it = 0; it < 16; it++) {
            int c = it * 8 + c8;
            xt[c][pp] = x[(size_t)(n * CC + c) * HW + p0 + pp];
        }
    }
    __syncthreads();
    {
        int pp2 = t >> 3, cb = t & 7;
        float s = 0.f;
        #pragma unroll
        for (int u = 0; u < 16; u++) s += xt[cb + u * 8][pp2];
        s += __shfl_xor(s, 1); s += __shfl_xor(s, 2); s += __shfl_xor(s, 4);
        float mu = s * (1.0f / CC);
        float v = 0.f;
        #pragma unroll
        for (int u = 0; u < 16; u++) { float d = xt[cb + u * 8][pp2] - mu; v += d * d; }
        v += __shfl_xor(v, 1); v += __shfl_xor(v, 2); v += __shfl_xor(v, 4);
        if (cb == 0) { mus[pp2] = mu; rss[pp2] = rsqrtf(v * (1.0f / CC) + 1e-5f); }
    }
    __syncthreads();
    {
        #pragma unroll
        for (int it = 0; it < 2; it++) {
            int pp2 = (t >> 4) + it * 16;
            int c0  = (t & 15) * 8;
            float mu = mus[pp2], rs = rss[pp2];
            int m = n * HW + p0 + pp2;
            short8 o;
            #pragma unroll
            for (int u = 0; u < 8; u++)
                o[u] = (short)f2bf((xt[c0 + u][pp2] - mu) * rs * w[c0 + u] + b[c0 + u]);
            *(short8*)(out + (size_t)m * CC + c0) = o;
        }
    }
}

// ---------------- K=128 GEMM body: bf16 [n][k] weights, vector stage --
template<int ACT>
__device__ __forceinline__ void k128_body(
    const BF* __restrict__ A, const BF* __restrict__ Bt,
    const float* __restrict__ bias, BF* __restrict__ Cout,
    int N, int row0, int col0, BF* Bl /* [64][LDK128] */)
{
    const int t = threadIdx.x;
    const int w = t >> 6, lane = t & 63, q = lane >> 4, r16 = lane & 15;
    {   // stage 64 cols x 128 k bf16: 4 uint4 per thread (vector copy)
        int nn = t >> 2;
        int kk = (t & 3) * 32;
        const BF* src = Bt + (size_t)(col0 + nn) * 128 + kk;
        #pragma unroll
        for (int u = 0; u < 4; u++)
            *(uint4*)(Bl + nn * LDK128 + kk + u * 8) = *(const uint4*)(src + u * 8);
    }
    __syncthreads();
    floatx4 acc[4] = {};
    const BF* arow = A + (size_t)(row0 + w * 16 + r16) * CC;
    #pragma unroll
    for (int ks = 0; ks < 4; ks++) {
        short8 af = *(const short8*)(arow + ks * 32 + q * 8);
        #pragma unroll
        for (int nt = 0; nt < 4; nt++) {
            short8 bf = *(const short8*)(Bl + (nt * 16 + r16) * LDK128 + ks * 32 + q * 8);
            acc[nt] = __builtin_amdgcn_mfma_f32_16x16x32_bf16(af, bf, acc[nt], 0, 0, 0);
        }
    }
    #pragma unroll
    for (int nt = 0; nt < 4; nt++) {
        int col = col0 + nt * 16 + r16;
        float bv = bias[col];
        #pragma unroll
        for (int reg = 0; reg < 4; reg++) {
            int row = row0 + w * 16 + q * 4 + reg;
            float v = acc[nt][reg] + bv;
            if (ACT == 1) v = gelu_f(v);
            Cout[(size_t)row * N + col] = f2bf(v);
        }
    }
}

// ---------------- phase2: qkv GEMM blocks + conv-MLP blocks -----------
__global__ __launch_bounds__(256) void phase2(
    const BF* __restrict__ xn, const BF* __restrict__ qkvT,
    const float* __restrict__ qkv_b, BF* __restrict__ qkv_out,
    const BF* __restrict__ c1T, const float* __restrict__ b1,
    const BF* __restrict__ c2T, const float* __restrict__ b2,
    BF* __restrict__ tout, float* __restrict__ part)
{
    __shared__ __align__(16) char smem[26624];
    const int bid = blockIdx.x;
    const int t = threadIdx.x;
    const int w = t >> 6, lane = t & 63, q = lane >> 4, r16 = lane & 15;

    if (bid < 1536) {
        int col0 = (bid % 6) * 64;
        int row0 = (bid / 6) * 64;
        k128_body<0>(xn, qkvT, qkv_b, qkv_out, 384, row0, col0, (BF*)smem);
        return;
    }
    // ---- conv branch ----
    BF*    W1l = (BF*)smem;                  // [32][LDK128]  8704 B
    BF*    W2l = (BF*)(smem + 8704);         // [128][LDK]   10240 B
    BF*    Hl  = (BF*)(smem + 18944);        // [64][LDK]     5120 B
    float* red = (float*)(smem + 24064);     // [4][128]      2048 B
    const int row0 = (bid - 1536) * 64;
    {   // stage W1: 32x128 bf16 = 512 uint4, 2/thread
        #pragma unroll
        for (int it = 0; it < 2; it++) {
            int idx = it * 256 + t;
            int nn = idx >> 4, u = idx & 15;
            *(uint4*)(W1l + nn * LDK128 + u * 8) = *(const uint4*)(c1T + nn * 128 + u * 8);
        }
    }
    {   // stage W2: 128x32 bf16 = 512 uint4, 2/thread
        #pragma unroll
        for (int it = 0; it < 2; it++) {
            int idx = it * 256 + t;
            int nn = idx >> 2, u = idx & 3;
            *(uint4*)(W2l + nn * LDK + u * 8) = *(const uint4*)(c2T + nn * 32 + u * 8);
        }
    }
    __syncthreads();
    floatx4 a1[2] = {};
    const BF* arow = xn + (size_t)(row0 + w * 16 + r16) * CC;
    #pragma unroll
    for (int ks = 0; ks < 4; ks++) {
        short8 af = *(const short8*)(arow + ks * 32 + q * 8);
        #pragma unroll
        for (int nt = 0; nt < 2; nt++) {
            short8 bf = *(const short8*)(W1l + (nt * 16 + r16) * LDK128 + ks * 32 + q * 8);
            a1[nt] = __builtin_amdgcn_mfma_f32_16x16x32_bf16(af, bf, a1[nt], 0, 0, 0);
        }
    }
    #pragma unroll
    for (int nt = 0; nt < 2; nt++) {
        int col = nt * 16 + r16;
        float bv = b1[col];
        #pragma unroll
        for (int reg = 0; reg < 4; reg++)
            Hl[(w * 16 + q * 4 + reg) * LDK + col] = f2bf(gelu_f(a1[nt][reg] + bv));
    }
    __syncthreads();
    floatx4 a2[8] = {};
    short8 af2 = *(const short8*)(Hl + (w * 16 + r16) * LDK + q * 8);
    #pragma unroll
    for (int nt = 0; nt < 8; nt++) {
        short8 bf = *(const short8*)(W2l + (nt * 16 + r16) * LDK + q * 8);
        a2[nt] = __builtin_amdgcn_mfma_f32_16x16x32_bf16(af2, bf, a2[nt], 0, 0, 0);
    }
    #pragma unroll
    for (int nt = 0; nt < 8; nt++) {
        int col = nt * 16 + r16;
        float bv = b2[col];
        float s = 0.f;
        #pragma unroll
        for (int reg = 0; reg < 4; reg++) {
            int row = row0 + w * 16 + q * 4 + reg;
            float v = a2[nt][reg] + bv;
            tout[(size_t)row * CC + col] = f2bf(v);
            s += v;
        }
        s += __shfl_xor(s, 16);
        s += __shfl_xor(s, 32);
        if (lane < 16) red[w * 128 + col] = s;
    }
    __syncthreads();
    if (t < 128) {
        float cs = red[t] + red[128 + t] + red[256 + t] + red[384 + t];
        atomicAdd(&part[(row0 >> 12) * CC + t], cs);
    }
}

// ---------------- standalone K=128 GEMM (fc1) -------------------------
template<int ACT>
__global__ __launch_bounds__(256) void gemm_k128(
    const BF* __restrict__ A, const BF* __restrict__ Bt,
    const float* __restrict__ bias, BF* __restrict__ Cout, int N)
{
    __shared__ __align__(16) BF Bl[64 * LDK128];
    k128_body<ACT>(A, Bt, bias, Cout, N, blockIdx.y * 64, blockIdx.x * 64, Bl);
}

// ---------------- MFMA neighborhood attention (unchanged R9) ----------
__global__ __launch_bounds__(256) void na_mfma_kernel(
    const BF* __restrict__ qkv, const float* __restrict__ rpb,
    BF* __restrict__ outp)
{
    __shared__ __align__(16) BF Kt[224][40];
    __shared__ __align__(16) BF Vt[32][232];
    __shared__ __align__(16) BF Qb[64][40];
    __shared__ __align__(16) BF Pl[4][16][232];
    __shared__ float rb[169];

    const int b = blockIdx.x;
    const int h = b & 3;
    const int tile = b >> 2;
    const int n = tile >> 6;
    const int ti = (tile >> 3) & 7, tj = tile & 7;
    const int t = threadIdx.x;
    const int w = t >> 6, lane = t & 63, quad = lane >> 4, r16 = lane & 15;
    const int i0 = ti * 8, j0 = tj * 8;
    const int wi0 = max(i0 - 3, 0), wj0 = max(j0 - 3, 0);
    const int R  = min(wi0 + 13, 63) - wi0 + 1;
    const int Rj = min(wj0 + 13, 63) - wj0 + 1;

    for (int idx = t; idx < 896; idx += 256) {
        int key = idx >> 2, ch = idx & 3;
        int kr = key >> 4, kc = key & 15;
        uint4 v = {0u, 0u, 0u, 0u};
        if (kr < R && kc < Rj) {
            size_t pix = (size_t)((n * HH + wi0 + kr) * WW + wj0 + kc);
            v = *(const uint4*)(qkv + pix * 384 + 128 + h * DD + ch * 8);
        }
        *(uint4*)&Kt[key][ch * 8] = v;
    }
    for (int idx = t; idx < 896; idx += 256) {
        int key = idx >> 2, ch = idx & 3;
        int kr = key >> 4, kc = key & 15;
        if (kr < R && kc < Rj) {
            size_t pix = (size_t)((n * HH + wi0 + kr) * WW + wj0 + kc);
            uint4 v = *(const uint4*)(qkv + pix * 384 + 256 + h * DD + ch * 8);
            const BF* pv = (const BF*)&v;
            #pragma unroll
            for (int u = 0; u < 8; u++) Vt[ch * 8 + u][key] = pv[u];
        } else {
            #pragma unroll
            for (int u = 0; u < 8; u++) Vt[ch * 8 + u][key] = 0;
        }
    }
    {
        int q = t >> 2, ch = t & 3;
        size_t mq = (size_t)((n * HH + i0 + (q >> 3)) * WW + j0 + (q & 7));
        *(uint4*)&Qb[q][ch * 8] = *(const uint4*)(qkv + mq * 384 + h * DD + ch * 8);
    }
    if (t < 169) rb[t] = rpb[h * 169 + t];
    __syncthreads();

    int oi[4], cok[4], bj0[4], ai_[4];
    #pragma unroll
    for (int reg = 0; reg < 4; reg++) {
        int q = w * 16 + quad * 4 + reg;
        int i = i0 + (q >> 3), j = j0 + (q & 7);
        int ni = min(max(i - 3, 0), HH - KS), nj = min(max(j - 3, 0), WW - KS);
        oi[reg]  = ni - wi0;
        ai_[reg] = ni - i + 6;
        int dc = r16 - (nj - wj0);
        cok[reg] = ((unsigned)dc < 7u) ? 1 : 0;
        bj0[reg] = min(max(dc + (nj - j + 6), 0), 12);
    }

    short8 aq = *(const short8*)&Qb[w * 16 + r16][quad * 8];
    floatx4 S[14];
    #pragma unroll
    for (int nt = 0; nt < 14; nt++) {
        floatx4 z = {0.f, 0.f, 0.f, 0.f};
        short8 bk = *(const short8*)&Kt[nt * 16 + r16][quad * 8];
        S[nt] = __builtin_amdgcn_mfma_f32_16x16x32_bf16(aq, bk, z, 0, 0, 0);
    }
    const float scale = 0.17677669529663688110f;
    #pragma unroll
    for (int nt = 0; nt < 14; nt++) {
        #pragma unroll
        for (int reg = 0; reg < 4; reg++) {
            int dr = nt - oi[reg];
            bool ok = ((unsigned)dr < 7u) && cok[reg];
            int bi = min(max(dr + ai_[reg], 0), 12);
            float bias = rb[bi * 13 + bj0[reg]];
            S[nt][reg] = ok ? fmaf(S[nt][reg], scale, bias) : -1e30f;
        }
    }
    float rinv[4];
    #pragma unroll
    for (int reg = 0; reg < 4; reg++) {
        float m = S[0][reg];
        #pragma unroll
        for (int nt = 1; nt < 14; nt++) m = fmaxf(m, S[nt][reg]);
        m = fmaxf(m, __shfl_xor(m, 1));
        m = fmaxf(m, __shfl_xor(m, 2));
        m = fmaxf(m, __shfl_xor(m, 4));
        m = fmaxf(m, __shfl_xor(m, 8));
        float s = 0.f;
        #pragma unroll
        for (int nt = 0; nt < 14; nt++) {
            float e = __expf(S[nt][reg] - m);
            S[nt][reg] = e;
            s += e;
        }
        s += __shfl_xor(s, 1);
        s += __shfl_xor(s, 2);
        s += __shfl_xor(s, 4);
        s += __shfl_xor(s, 8);
        rinv[reg] = 1.0f / s;
    }
    #pragma unroll
    for (int nt = 0; nt < 14; nt++)
        #pragma unroll
        for (int reg = 0; reg < 4; reg++)
            Pl[w][quad * 4 + reg][nt * 16 + r16] = f2bf(S[nt][reg] * rinv[reg]);

    floatx4 O0 = {0.f, 0.f, 0.f, 0.f}, O1 = {0.f, 0.f, 0.f, 0.f};
    #pragma unroll
    for (int ks = 0; ks < 7; ks++) {
        short8 ap = *(const short8*)&Pl[w][r16][ks * 32 + quad * 8];
        short8 b0 = *(const short8*)&Vt[r16][ks * 32 + quad * 8];
        short8 b1 = *(const short8*)&Vt[16 + r16][ks * 32 + quad * 8];
        O0 = __builtin_amdgcn_mfma_f32_16x16x32_bf16(ap, b0, O0, 0, 0, 0);
        O1 = __builtin_amdgcn_mfma_f32_16x16x32_bf16(ap, b1, O1, 0, 0, 0);
    }
    #pragma unroll
    for (int reg = 0; reg < 4; reg++) {
        int q = w * 16 + quad * 4 + reg;
        size_t m = (size_t)((n * HH + i0 + (q >> 3)) * WW + j0 + (q & 7));
        outp[m * CC + h * DD + r16]      = f2bf(O0[reg]);
        outp[m * CC + h * DD + 16 + r16] = f2bf(O1[reg]);
    }
}

// ---------------- fused CA-gate + proj GEMM + x2 + LN2 ----------------
__global__ __launch_bounds__(256) void projx2ln2g(
    const BF* __restrict__ A, const BF* __restrict__ projT,
    const float* __restrict__ bias, const float* __restrict__ x,
    const BF* __restrict__ tbuf, const float* __restrict__ part,
    const float* __restrict__ ca1_w, const float* __restrict__ ca1_b,
    const float* __restrict__ ca2_w, const float* __restrict__ ca2_b,
    const float* __restrict__ w2, const float* __restrict__ b2,
    float* __restrict__ x2b, BF* __restrict__ lnout)
{
    __shared__ __align__(16) BF Bl[128 * LDK128];   // 34816 B
    __shared__ float xs[64][132];                   // [p][c] 33792 B
    __shared__ float gs[128];
    __shared__ float h1[7];
    __shared__ float gl[128];

    const int t = threadIdx.x;
    const int w = t >> 6, lane = t & 63, q = lane >> 4, r16 = lane & 15;
    const int row0 = blockIdx.x * 64;
    const int n = row0 >> 12;
    const int p0 = row0 & 4095;

    {   // stage projT 128x128 bf16 = 2048 uint4, 8/thread
        #pragma unroll
        for (int it = 0; it < 8; it++) {
            int idx = it * 256 + t;
            int nn = idx >> 4, u = idx & 15;
            *(uint4*)(Bl + nn * LDK128 + u * 8) = *(const uint4*)(projT + nn * 128 + u * 8);
        }
    }
    {   // stage x tile coalesced: 128 c x 64 p; float4 along p
        #pragma unroll
        for (int it = 0; it < 8; it++) {
            int idx4 = it * 256 + t;
            int p4 = idx4 & 15, c = idx4 >> 4;
            float4 v = *(const float4*)(x + (size_t)(n * CC + c) * HW + p0 + p4 * 4);
            xs[p4 * 4 + 0][c] = v.x; xs[p4 * 4 + 1][c] = v.y;
            xs[p4 * 4 + 2][c] = v.z; xs[p4 * 4 + 3][c] = v.w;
        }
    }
    if (t < 128) gs[t] = part[n * CC + t] * (1.0f / HW);
    __syncthreads();
    if (t < 7) {
        float a = ca1_b[t];
        for (int k = 0; k < 128; k++) a += gs[k] * ca1_w[k * 7 + t];
        h1[t] = fmaxf(a, 0.f);
    }
    __syncthreads();
    if (t < 128) {
        float o = ca2_b[t];
        #pragma unroll
        for (int r = 0; r < 7; r++) o += h1[r] * ca2_w[r * 128 + t];
        gl[t] = 1.0f / (1.0f + expf(-o));
    }

    floatx4 acc[8] = {};
    const BF* arow = A + (size_t)(row0 + w * 16 + r16) * CC;
    #pragma unroll
    for (int ks = 0; ks < 4; ks++) {
        short8 af = *(const short8*)(arow + ks * 32 + q * 8);
        #pragma unroll
        for (int nt = 0; nt < 8; nt++) {
            short8 bf = *(const short8*)(Bl + (nt * 16 + r16) * LDK128 + ks * 32 + q * 8);
            acc[nt] = __builtin_amdgcn_mfma_f32_16x16x32_bf16(af, bf, acc[nt], 0, 0, 0);
        }
    }
    __syncthreads();   // gl ready

    float s1[4] = {0.f, 0.f, 0.f, 0.f}, s2[4] = {0.f, 0.f, 0.f, 0.f};
    #pragma unroll
    for (int nt = 0; nt < 8; nt++) {
        int col = nt * 16 + r16;
        float bv = bias[col];
        float gv = gl[col];
        #pragma unroll
        for (int reg = 0; reg < 4; reg++) {
            int lr = w * 16 + q * 4 + reg;
            int row = row0 + lr;
            float xv = xs[lr][col];
            float tv = bf2f(tbuf[(size_t)row * CC + col]);
            float v = acc[nt][reg] + bv + xv + 0.02f * tv * gv;
            acc[nt][reg] = v;
            s1[reg] += v;
            s2[reg] += v * v;
        }
    }
    #pragma unroll
    for (int reg = 0; reg < 4; reg++) {
        #pragma unroll
        for (int off = 8; off; off >>= 1) {
            s1[reg] += __shfl_xor(s1[reg], off);
            s2[reg] += __shfl_xor(s2[reg], off);
        }
    }
    float mu[4], rr[4];
    #pragma unroll
    for (int reg = 0; reg < 4; reg++) {
        mu[reg] = s1[reg] * (1.0f / CC);
        float var = s2[reg] * (1.0f / CC) - mu[reg] * mu[reg];
        rr[reg] = rsqrtf(var + 1e-5f);
    }
    #pragma unroll
    for (int nt = 0; nt < 8; nt++) {
        int col = nt * 16 + r16;
        float wv = w2[col], bv2 = b2[col];
        #pragma unroll
        for (int reg = 0; reg < 4; reg++) {
            int row = row0 + w * 16 + q * 4 + reg;
            float v = acc[nt][reg];
            x2b[(size_t)row * CC + col] = v;
            lnout[(size_t)row * CC + col] = f2bf((v - mu[reg]) * rr[reg] * wv + bv2);
        }
    }
}

// ---------------- fc2: K=512 GEMM + x2b + coalesced NCHW store --------
__global__ __launch_bounds__(256) void fc2_kernel(
    const BF* __restrict__ A, const BF* __restrict__ fc2T,
    const float* __restrict__ bias, const float* __restrict__ x2b,
    float* __restrict__ out)
{
    __shared__ __align__(16) BF Alds[64][LDK];
    __shared__ __align__(16) BF Blds[64][LDK];   // [n][k]
    __shared__ float st[64][66];                 // [col][p] 16896 B

    const int t    = threadIdx.x;
    const int w    = t >> 6;
    const int lane = t & 63;
    const int q    = lane >> 4;
    const int r16  = lane & 15;
    const int row0 = blockIdx.y * 64;
    const int col0 = blockIdx.x * 64;
    const int n    = row0 >> 12;
    const int p0   = row0 & 4095;

    floatx4 acc[4] = {};
    const int ar = t >> 2;
    const int ak = (t & 3) * 8;
    const int bnn = t >> 2;            // B stage: col within tile
    const int bko = (t & 3) * 8;       // B stage: k offset within chunk

    for (int k0 = 0; k0 < 512; k0 += 32) {
        *(short8*)(&Alds[ar][ak]) =
            *(const short8*)(A + (size_t)(row0 + ar) * 512 + k0 + ak);
        // B: 64 cols x 32 k bf16 from fc2T [n][512], one uint4 per thread
        *(uint4*)(&Blds[bnn][bko]) =
            *(const uint4*)(fc2T + (size_t)(col0 + bnn) * 512 + k0 + bko);
        __syncthreads();
        short8 af = *(const short8*)(&Alds[w * 16 + r16][q * 8]);
        short8 bfm[4];
        #pragma unroll
        for (int nt = 0; nt < 4; nt++)
            bfm[nt] = *(const short8*)(&Blds[nt * 16 + r16][q * 8]);
        #pragma unroll
        for (int nt = 0; nt < 4; nt++)
            acc[nt] = __builtin_amdgcn_mfma_f32_16x16x32_bf16(af, bfm[nt], acc[nt], 0, 0, 0);
        __syncthreads();
    }

    #pragma unroll
    for (int nt = 0; nt < 4; nt++) {
        int col = col0 + nt * 16 + r16;
        float bv = bias[col];
        #pragma unroll
        for (int reg = 0; reg < 4; reg++) {
            int lr = w * 16 + q * 4 + reg;
            int row = row0 + lr;
            st[nt * 16 + r16][lr] = acc[nt][reg] + bv + x2b[(size_t)row * CC + col];
        }
    }
    __syncthreads();
    {
        int cc = t >> 2, ch = (t & 3) * 16;
        float* dst = out + (size_t)(n * CC + col0 + cc) * HW + p0 + ch;
        #pragma unroll
        for (int u = 0; u < 4; u++) {
            float4 v;
            v.x = st[cc][ch + u * 4 + 0];
            v.y = st[cc][ch + u * 4 + 1];
            v.z = st[cc][ch + u * 4 + 2];
            v.w = st[cc][ch + u * 4 + 3];
            *(float4*)(dst + u * 4) = v;
        }
    }
}

extern "C" void kernel_launch(void* const* d_in, const int* in_sizes, int n_in,
                              void* d_out, int out_size, void* d_ws, size_t ws_size,
                              hipStream_t stream)
{
    const float* x       = (const float*)d_in[0];
    const float* ln1_w   = (const float*)d_in[1];
    const float* ln1_b   = (const float*)d_in[2];
    const float* ln2_w   = (const float*)d_in[3];
    const float* ln2_b   = (const float*)d_in[4];
    const float* qkv_w   = (const float*)d_in[5];
    const float* qkv_b   = (const float*)d_in[6];
    const float* proj_w  = (const float*)d_in[7];
    const float* proj_b  = (const float*)d_in[8];
    const float* rpb     = (const float*)d_in[9];
    const float* conv1_w = (const float*)d_in[10];
    const float* conv1_b = (const float*)d_in[11];
    const float* conv2_w = (const float*)d_in[12];
    const float* conv2_b = (const float*)d_in[13];
    const float* ca1_w   = (const float*)d_in[14];
    const float* ca1_b   = (const float*)d_in[15];
    const float* ca2_w   = (const float*)d_in[16];
    const float* ca2_b   = (const float*)d_in[17];
    const float* fc1_w   = (const float*)d_in[18];
    const float* fc1_b   = (const float*)d_in[19];
    const float* fc2_w   = (const float*)d_in[20];
    const float* fc2_b   = (const float*)d_in[21];
    float* out = (float*)d_out;

    // workspace (bytes). hbuf_bf overlays xn_bf+qkv_bf (both dead by fc1).
    char* ws = (char*)d_ws;
    BF*    xn_bf   = (BF*)(ws);                  // M*128*2 = 4 MB
    BF*    qkv_bf  = (BF*)(ws + 4194304);        // M*384*2 = 12 MB
    BF*    hbuf_bf = (BF*)(ws);                  // M*512*2 = 16 MB (overlay)
    BF*    t_bf    = (BF*)(ws + 16777216);       // M*128*2 = 4 MB
    float* x2b     = (float*)(ws + 25165824);    // M*128*4 = 8 MB
    BF*    na_bf   = (BF*)(ws + 33554432);       // M*128*2 = 4 MB
    BF*    ln2_bf  = (BF*)(ws + 37748736);       // M*128*2 = 4 MB
    float* part    = (float*)(ws + 41943040);    // 2 KB
    BF*    qkvT    = (BF*)(ws + 41945088);       // 98304 B
    BF*    c1T     = (BF*)(ws + 42043392);       // 8192 B
    BF*    c2T     = (BF*)(ws + 42051584);       // 8192 B
    BF*    projT   = (BF*)(ws + 42059776);       // 32768 B
    BF*    fc1T    = (BF*)(ws + 42092544);       // 131072 B
    BF*    fc2T    = (BF*)(ws + 42223616);       // 131072 B

    // 1. LN1 transpose-tile + one-time weight prep (blocks 512..639)
    ln1t_kernel<<<640, 256, 0, stream>>>(x, ln1_w, ln1_b, xn_bf, part,
        qkv_w, conv1_w, conv2_w, proj_w, fc1_w, fc2_w,
        qkvT, c1T, c2T, projT, fc1T, fc2T);
    // 2. qkv GEMM + conv-MLP (+column sums), one launch
    phase2<<<1792, 256, 0, stream>>>(xn_bf, qkvT, qkv_b, qkv_bf,
                                     c1T, conv1_b, c2T, conv2_b, t_bf, part);
    // 3. MFMA neighborhood attention
    na_mfma_kernel<<<1024, 256, 0, stream>>>(qkv_bf, rpb, na_bf);
    // 4. CA gate + proj + x2 residual + LN2 (coalesced x staging)
    projx2ln2g<<<256, 256, 0, stream>>>(na_bf, projT, proj_b, x, t_bf, part,
                                        ca1_w, ca1_b, ca2_w, ca2_b,
                                        ln2_w, ln2_b, x2b, ln2_bf);
    // 5. fc1: (M,128)@(128,512)+gelu -> bf16 (overlays xn/qkv)
    gemm_k128<1><<<dim3(8, 256), 256, 0, stream>>>(ln2_bf, fc1T, fc1_b, hbuf_bf, 512);
    // 6. fc2: K=512 + x2b, coalesced NHWC->NCHW store
    fc2_kernel<<<dim3(2, 256), 256, 0, stream>>>(hbuf_bf, fc2T, fc2_b, x2b, out);
}

// Round 12
// 172.636 us; speedup vs baseline: 1.3171x; 1.0115x over previous
//
#include <hip/hip_runtime.h>
#include <hip/hip_bf16.h>
#include <math.h>

#define NB 4
#define CC 128
#define HH 64
#define WW 64
#define HEADS 4
#define KS 7
#define DD 32
#define HW 4096
#define MTOT 16384   // NB*HW

typedef unsigned short BF;
typedef short short8 __attribute__((ext_vector_type(8)));
typedef float floatx4 __attribute__((ext_vector_type(4)));

__device__ __forceinline__ float gelu_f(float x) {
    return 0.5f * x * (1.0f + erff(x * 0.70710678118654752440f));
}

__device__ __forceinline__ BF f2bf(float f) {
    union { float f; unsigned u; } a; a.f = f;
    unsigned u = a.u;
    unsigned r = u + 0x7FFFu + ((u >> 16) & 1u);   // RNE
    return (BF)(r >> 16);
}

__device__ __forceinline__ float bf2f(BF v) {
    return __uint_as_float(((unsigned)v) << 16);
}

#define LDK 40      // padded LDS row, K=32 tiles (bf16)
#define LDK128 136  // padded LDS row, K=128 tiles (bf16)

// ---------------- LN1 transpose-tile + one-time weight prep -----------
// blocks [0,512): LN1 NCHW -> bf16 NHWC rows
// blocks [512,640): weights -> bf16. qkv/c1/c2: [n][k]. proj/fc1/fc2:
// fragment-coalesced tiles [kstep][n][32] (64-lane frag load = 1 KB stream)
__global__ __launch_bounds__(256) void ln1t_kernel(
    const float* __restrict__ x, const float* __restrict__ w,
    const float* __restrict__ b, BF* __restrict__ out,
    float* __restrict__ part,
    const float* __restrict__ qkv_w, const float* __restrict__ conv1_w,
    const float* __restrict__ conv2_w, const float* __restrict__ proj_w,
    const float* __restrict__ fc1_w, const float* __restrict__ fc2_w,
    BF* __restrict__ qkvT, BF* __restrict__ c1T, BF* __restrict__ c2T,
    BF* __restrict__ projT2, BF* __restrict__ fc1T2, BF* __restrict__ fc2T2)
{
    const int blk = blockIdx.x;
    const int t  = threadIdx.x;

    if (blk >= 512) {   // ---- weight prep (one-time, 204800 elems) ----
        for (int idx = (blk - 512) * 256 + t; idx < 204800; idx += 32768) {
            if (idx < 49152) {                    // qkvT [384][128]
                int l = idx, n = l >> 7, k = l & 127;
                qkvT[l] = f2bf(qkv_w[k * 384 + n]);
            } else if (idx < 53248) {             // c1T [32][128]
                int l = idx - 49152, n = l >> 7, k = l & 127;
                c1T[l] = f2bf(conv1_w[k * 32 + n]);
            } else if (idx < 57344) {             // c2T [128][32]
                int l = idx - 53248, n = l >> 5, k = l & 31;
                c2T[l] = f2bf(conv2_w[k * 128 + n]);
            } else if (idx < 73728) {             // projT2 [4][128][32]
                int l = idx - 57344, kk = l & 31, n = (l >> 5) & 127, ks = l >> 12;
                projT2[l] = f2bf(proj_w[(ks * 32 + kk) * 128 + n]);
            } else if (idx < 139264) {            // fc1T2 [4][512][32]
                int l = idx - 73728, kk = l & 31, n = (l >> 5) & 511, ks = l >> 14;
                fc1T2[l] = f2bf(fc1_w[(ks * 32 + kk) * 512 + n]);
            } else {                              // fc2T2 [16][128][32]
                int l = idx - 139264, kk = l & 31, n = (l >> 5) & 127, ks = l >> 12;
                fc2T2[l] = f2bf(fc2_w[(ks * 32 + kk) * 128 + n]);
            }
        }
        return;
    }

    __shared__ float xt[128][33];
    __shared__ float mus[32], rss[32];
    const int n  = blk >> 7;
    const int p0 = (blk & 127) * 32;
    if (blk < 4 && t < 128) part[blk * CC + t] = 0.f;   // zero CA partials

    {
        int pp = t & 31, c8 = t >> 5;
        #pragma unroll 4
        for (int it = 0; it < 16; it++) {
            int c = it * 8 + c8;
            xt[c][pp] = x[(size_t)(n * CC + c) * HW + p0 + pp];
        }
    }
    __syncthreads();
    {
        int pp2 = t >> 3, cb = t & 7;
        float s = 0.f;
        #pragma unroll
        for (int u = 0; u < 16; u++) s += xt[cb + u * 8][pp2];
        s += __shfl_xor(s, 1); s += __shfl_xor(s, 2); s += __shfl_xor(s, 4);
        float mu = s * (1.0f / CC);
        float v = 0.f;
        #pragma unroll
        for (int u = 0; u < 16; u++) { float d = xt[cb + u * 8][pp2] - mu; v += d * d; }
        v += __shfl_xor(v, 1); v += __shfl_xor(v, 2); v += __shfl_xor(v, 4);
        if (cb == 0) { mus[pp2] = mu; rss[pp2] = rsqrtf(v * (1.0f / CC) + 1e-5f); }
    }
    __syncthreads();
    {
        #pragma unroll
        for (int it = 0; it < 2; it++) {
            int pp2 = (t >> 4) + it * 16;
            int c0  = (t & 15) * 8;
            float mu = mus[pp2], rs = rss[pp2];
            int m = n * HW + p0 + pp2;
            short8 o;
            #pragma unroll
            for (int u = 0; u < 8; u++)
                o[u] = (short)f2bf((xt[c0 + u][pp2] - mu) * rs * w[c0 + u] + b[c0 + u]);
            *(short8*)(out + (size_t)m * CC + c0) = o;
        }
    }
}

// ---------------- K=128 GEMM body: bf16 [n][k] weights, vector stage --
template<int ACT>
__device__ __forceinline__ void k128_body(
    const BF* __restrict__ A, const BF* __restrict__ Bt,
    const float* __restrict__ bias, BF* __restrict__ Cout,
    int N, int row0, int col0, BF* Bl /* [64][LDK128] */)
{
    const int t = threadIdx.x;
    const int w = t >> 6, lane = t & 63, q = lane >> 4, r16 = lane & 15;
    {   // stage 64 cols x 128 k bf16: 4 uint4 per thread (vector copy)
        int nn = t >> 2;
        int kk = (t & 3) * 32;
        const BF* src = Bt + (size_t)(col0 + nn) * 128 + kk;
        #pragma unroll
        for (int u = 0; u < 4; u++)
            *(uint4*)(Bl + nn * LDK128 + kk + u * 8) = *(const uint4*)(src + u * 8);
    }
    __syncthreads();
    floatx4 acc[4] = {};
    const BF* arow = A + (size_t)(row0 + w * 16 + r16) * CC;
    #pragma unroll
    for (int ks = 0; ks < 4; ks++) {
        short8 af = *(const short8*)(arow + ks * 32 + q * 8);
        #pragma unroll
        for (int nt = 0; nt < 4; nt++) {
            short8 bf = *(const short8*)(Bl + (nt * 16 + r16) * LDK128 + ks * 32 + q * 8);
            acc[nt] = __builtin_amdgcn_mfma_f32_16x16x32_bf16(af, bf, acc[nt], 0, 0, 0);
        }
    }
    #pragma unroll
    for (int nt = 0; nt < 4; nt++) {
        int col = col0 + nt * 16 + r16;
        float bv = bias[col];
        #pragma unroll
        for (int reg = 0; reg < 4; reg++) {
            int row = row0 + w * 16 + q * 4 + reg;
            float v = acc[nt][reg] + bv;
            if (ACT == 1) v = gelu_f(v);
            Cout[(size_t)row * N + col] = f2bf(v);
        }
    }
}

// ---------------- phase2: qkv GEMM blocks + conv-MLP blocks -----------
__global__ __launch_bounds__(256) void phase2(
    const BF* __restrict__ xn, const BF* __restrict__ qkvT,
    const float* __restrict__ qkv_b, BF* __restrict__ qkv_out,
    const BF* __restrict__ c1T, const float* __restrict__ b1,
    const BF* __restrict__ c2T, const float* __restrict__ b2,
    BF* __restrict__ tout, float* __restrict__ part)
{
    __shared__ __align__(16) char smem[26624];
    const int bid = blockIdx.x;
    const int t = threadIdx.x;
    const int w = t >> 6, lane = t & 63, q = lane >> 4, r16 = lane & 15;

    if (bid < 1536) {
        int col0 = (bid % 6) * 64;
        int row0 = (bid / 6) * 64;
        k128_body<0>(xn, qkvT, qkv_b, qkv_out, 384, row0, col0, (BF*)smem);
        return;
    }
    // ---- conv branch ----
    BF*    W1l = (BF*)smem;                  // [32][LDK128]  8704 B
    BF*    W2l = (BF*)(smem + 8704);         // [128][LDK]   10240 B
    BF*    Hl  = (BF*)(smem + 18944);        // [64][LDK]     5120 B
    float* red = (float*)(smem + 24064);     // [4][128]      2048 B
    const int row0 = (bid - 1536) * 64;
    {
        #pragma unroll
        for (int it = 0; it < 2; it++) {
            int idx = it * 256 + t;
            int nn = idx >> 4, u = idx & 15;
            *(uint4*)(W1l + nn * LDK128 + u * 8) = *(const uint4*)(c1T + nn * 128 + u * 8);
        }
    }
    {
        #pragma unroll
        for (int it = 0; it < 2; it++) {
            int idx = it * 256 + t;
            int nn = idx >> 2, u = idx & 3;
            *(uint4*)(W2l + nn * LDK + u * 8) = *(const uint4*)(c2T + nn * 32 + u * 8);
        }
    }
    __syncthreads();
    floatx4 a1[2] = {};
    const BF* arow = xn + (size_t)(row0 + w * 16 + r16) * CC;
    #pragma unroll
    for (int ks = 0; ks < 4; ks++) {
        short8 af = *(const short8*)(arow + ks * 32 + q * 8);
        #pragma unroll
        for (int nt = 0; nt < 2; nt++) {
            short8 bf = *(const short8*)(W1l + (nt * 16 + r16) * LDK128 + ks * 32 + q * 8);
            a1[nt] = __builtin_amdgcn_mfma_f32_16x16x32_bf16(af, bf, a1[nt], 0, 0, 0);
        }
    }
    #pragma unroll
    for (int nt = 0; nt < 2; nt++) {
        int col = nt * 16 + r16;
        float bv = b1[col];
        #pragma unroll
        for (int reg = 0; reg < 4; reg++)
            Hl[(w * 16 + q * 4 + reg) * LDK + col] = f2bf(gelu_f(a1[nt][reg] + bv));
    }
    __syncthreads();
    floatx4 a2[8] = {};
    short8 af2 = *(const short8*)(Hl + (w * 16 + r16) * LDK + q * 8);
    #pragma unroll
    for (int nt = 0; nt < 8; nt++) {
        short8 bf = *(const short8*)(W2l + (nt * 16 + r16) * LDK + q * 8);
        a2[nt] = __builtin_amdgcn_mfma_f32_16x16x32_bf16(af2, bf, a2[nt], 0, 0, 0);
    }
    #pragma unroll
    for (int nt = 0; nt < 8; nt++) {
        int col = nt * 16 + r16;
        float bv = b2[col];
        float s = 0.f;
        #pragma unroll
        for (int reg = 0; reg < 4; reg++) {
            int row = row0 + w * 16 + q * 4 + reg;
            float v = a2[nt][reg] + bv;
            tout[(size_t)row * CC + col] = f2bf(v);
            s += v;
        }
        s += __shfl_xor(s, 16);
        s += __shfl_xor(s, 32);
        if (lane < 16) red[w * 128 + col] = s;
    }
    __syncthreads();
    if (t < 128) {
        float cs = red[t] + red[128 + t] + red[256 + t] + red[384 + t];
        atomicAdd(&part[(row0 >> 12) * CC + t], cs);
    }
}

// ---------------- MFMA neighborhood attention (unchanged) -------------
__global__ __launch_bounds__(256) void na_mfma_kernel(
    const BF* __restrict__ qkv, const float* __restrict__ rpb,
    BF* __restrict__ outp)
{
    __shared__ __align__(16) BF Kt[224][40];
    __shared__ __align__(16) BF Vt[32][232];
    __shared__ __align__(16) BF Qb[64][40];
    __shared__ __align__(16) BF Pl[4][16][232];
    __shared__ float rb[169];

    const int b = blockIdx.x;
    const int h = b & 3;
    const int tile = b >> 2;
    const int n = tile >> 6;
    const int ti = (tile >> 3) & 7, tj = tile & 7;
    const int t = threadIdx.x;
    const int w = t >> 6, lane = t & 63, quad = lane >> 4, r16 = lane & 15;
    const int i0 = ti * 8, j0 = tj * 8;
    const int wi0 = max(i0 - 3, 0), wj0 = max(j0 - 3, 0);
    const int R  = min(wi0 + 13, 63) - wi0 + 1;
    const int Rj = min(wj0 + 13, 63) - wj0 + 1;

    for (int idx = t; idx < 896; idx += 256) {
        int key = idx >> 2, ch = idx & 3;
        int kr = key >> 4, kc = key & 15;
        uint4 v = {0u, 0u, 0u, 0u};
        if (kr < R && kc < Rj) {
            size_t pix = (size_t)((n * HH + wi0 + kr) * WW + wj0 + kc);
            v = *(const uint4*)(qkv + pix * 384 + 128 + h * DD + ch * 8);
        }
        *(uint4*)&Kt[key][ch * 8] = v;
    }
    for (int idx = t; idx < 896; idx += 256) {
        int key = idx >> 2, ch = idx & 3;
        int kr = key >> 4, kc = key & 15;
        if (kr < R && kc < Rj) {
            size_t pix = (size_t)((n * HH + wi0 + kr) * WW + wj0 + kc);
            uint4 v = *(const uint4*)(qkv + pix * 384 + 256 + h * DD + ch * 8);
            const BF* pv = (const BF*)&v;
            #pragma unroll
            for (int u = 0; u < 8; u++) Vt[ch * 8 + u][key] = pv[u];
        } else {
            #pragma unroll
            for (int u = 0; u < 8; u++) Vt[ch * 8 + u][key] = 0;
        }
    }
    {
        int q = t >> 2, ch = t & 3;
        size_t mq = (size_t)((n * HH + i0 + (q >> 3)) * WW + j0 + (q & 7));
        *(uint4*)&Qb[q][ch * 8] = *(const uint4*)(qkv + mq * 384 + h * DD + ch * 8);
    }
    if (t < 169) rb[t] = rpb[h * 169 + t];
    __syncthreads();

    int oi[4], cok[4], bj0[4], ai_[4];
    #pragma unroll
    for (int reg = 0; reg < 4; reg++) {
        int q = w * 16 + quad * 4 + reg;
        int i = i0 + (q >> 3), j = j0 + (q & 7);
        int ni = min(max(i - 3, 0), HH - KS), nj = min(max(j - 3, 0), WW - KS);
        oi[reg]  = ni - wi0;
        ai_[reg] = ni - i + 6;
        int dc = r16 - (nj - wj0);
        cok[reg] = ((unsigned)dc < 7u) ? 1 : 0;
        bj0[reg] = min(max(dc + (nj - j + 6), 0), 12);
    }

    short8 aq = *(const short8*)&Qb[w * 16 + r16][quad * 8];
    floatx4 S[14];
    #pragma unroll
    for (int nt = 0; nt < 14; nt++) {
        floatx4 z = {0.f, 0.f, 0.f, 0.f};
        short8 bk = *(const short8*)&Kt[nt * 16 + r16][quad * 8];
        S[nt] = __builtin_amdgcn_mfma_f32_16x16x32_bf16(aq, bk, z, 0, 0, 0);
    }
    const float scale = 0.17677669529663688110f;
    #pragma unroll
    for (int nt = 0; nt < 14; nt++) {
        #pragma unroll
        for (int reg = 0; reg < 4; reg++) {
            int dr = nt - oi[reg];
            bool ok = ((unsigned)dr < 7u) && cok[reg];
            int bi = min(max(dr + ai_[reg], 0), 12);
            float bias = rb[bi * 13 + bj0[reg]];
            S[nt][reg] = ok ? fmaf(S[nt][reg], scale, bias) : -1e30f;
        }
    }
    float rinv[4];
    #pragma unroll
    for (int reg = 0; reg < 4; reg++) {
        float m = S[0][reg];
        #pragma unroll
        for (int nt = 1; nt < 14; nt++) m = fmaxf(m, S[nt][reg]);
        m = fmaxf(m, __shfl_xor(m, 1));
        m = fmaxf(m, __shfl_xor(m, 2));
        m = fmaxf(m, __shfl_xor(m, 4));
        m = fmaxf(m, __shfl_xor(m, 8));
        float s = 0.f;
        #pragma unroll
        for (int nt = 0; nt < 14; nt++) {
            float e = __expf(S[nt][reg] - m);
            S[nt][reg] = e;
            s += e;
        }
        s += __shfl_xor(s, 1);
        s += __shfl_xor(s, 2);
        s += __shfl_xor(s, 4);
        s += __shfl_xor(s, 8);
        rinv[reg] = 1.0f / s;
    }
    #pragma unroll
    for (int nt = 0; nt < 14; nt++)
        #pragma unroll
        for (int reg = 0; reg < 4; reg++)
            Pl[w][quad * 4 + reg][nt * 16 + r16] = f2bf(S[nt][reg] * rinv[reg]);

    floatx4 O0 = {0.f, 0.f, 0.f, 0.f}, O1 = {0.f, 0.f, 0.f, 0.f};
    #pragma unroll
    for (int ks = 0; ks < 7; ks++) {
        short8 ap = *(const short8*)&Pl[w][r16][ks * 32 + quad * 8];
        short8 b0 = *(const short8*)&Vt[r16][ks * 32 + quad * 8];
        short8 b1 = *(const short8*)&Vt[16 + r16][ks * 32 + quad * 8];
        O0 = __builtin_amdgcn_mfma_f32_16x16x32_bf16(ap, b0, O0, 0, 0, 0);
        O1 = __builtin_amdgcn_mfma_f32_16x16x32_bf16(ap, b1, O1, 0, 0, 0);
    }
    #pragma unroll
    for (int reg = 0; reg < 4; reg++) {
        int q = w * 16 + quad * 4 + reg;
        size_t m = (size_t)((n * HH + i0 + (q >> 3)) * WW + j0 + (q & 7));
        outp[m * CC + h * DD + r16]      = f2bf(O0[reg]);
        outp[m * CC + h * DD + 16 + r16] = f2bf(O1[reg]);
    }
}

// ---------------- fused tail: proj + gate + x2 + LN2 + fc1 + fc2 ------
// block = 32 rows, 512 blocks (2/CU). wave: mt = w&1 (row half),
// nh = w>>1 (col half). x2 kept in registers (layout-aligned with fc2
// epilogue). h lives only in LDS. B-frags direct from global in
// fragment-coalesced [kstep][n][32] tiles (64-lane load = 1 KB stream).
__global__ __launch_bounds__(256) void tail_kernel(
    const BF* __restrict__ A, const BF* __restrict__ projT2,
    const float* __restrict__ proj_b, const float* __restrict__ x,
    const BF* __restrict__ tbuf, const float* __restrict__ part,
    const float* __restrict__ ca1_w, const float* __restrict__ ca1_b,
    const float* __restrict__ ca2_w, const float* __restrict__ ca2_b,
    const float* __restrict__ w2, const float* __restrict__ b2,
    const BF* __restrict__ fc1T2, const float* __restrict__ fc1_b,
    const BF* __restrict__ fc2T2, const float* __restrict__ fc2_b,
    float* __restrict__ out)
{
    __shared__ float xs[32][132];            // 16896 B  x tile [p][c]
    __shared__ __align__(16) BF ln2l[32][136];  // 8704 B
    __shared__ __align__(16) BF hl[32][520];    // 33280 B  fc1 out
    __shared__ float st[128][34];            // 17408 B  store tile [c][p]
    __shared__ float gs[128], h1s[7], gl[128];
    __shared__ float S1[4][16], S2[4][16];

    const int t = threadIdx.x;
    const int w = t >> 6, lane = t & 63, quad = lane >> 4, r16 = lane & 15;
    const int row0 = blockIdx.x * 32;
    const int n = row0 >> 12, p0 = row0 & 4095;
    const int mt = w & 1, nh = w >> 1;
    const int lr0 = mt * 16;

    // ---- stage x tile: 128 c x 32 p, coalesced float4 along p ----
    #pragma unroll
    for (int it = 0; it < 4; it++) {
        int idx4 = it * 256 + t;
        int p4 = idx4 & 7, c = idx4 >> 3;
        float4 v = *(const float4*)(x + (size_t)(n * CC + c) * HW + p0 + p4 * 4);
        xs[p4 * 4 + 0][c] = v.x; xs[p4 * 4 + 1][c] = v.y;
        xs[p4 * 4 + 2][c] = v.z; xs[p4 * 4 + 3][c] = v.w;
    }
    if (t < 128) gs[t] = part[n * CC + t] * (1.0f / HW);
    __syncthreads();
    if (t < 7) {
        float a = ca1_b[t];
        for (int k = 0; k < 128; k++) a += gs[k] * ca1_w[k * 7 + t];
        h1s[t] = fmaxf(a, 0.f);
    }
    __syncthreads();
    if (t < 128) {
        float o = ca2_b[t];
        #pragma unroll
        for (int r = 0; r < 7; r++) o += h1s[r] * ca2_w[r * 128 + t];
        gl[t] = 1.0f / (1.0f + expf(-o));
    }

    // ---- proj: wave = 16 rows x 64 cols ----
    floatx4 acc[4] = {};
    const BF* arow = A + (size_t)(row0 + lr0 + r16) * CC;
    #pragma unroll
    for (int ks = 0; ks < 4; ks++) {
        short8 af = *(const short8*)(arow + ks * 32 + quad * 8);
        #pragma unroll
        for (int nt = 0; nt < 4; nt++) {
            int col = nh * 64 + nt * 16 + r16;
            short8 bf = *(const short8*)(projT2 + ((size_t)(ks * 128 + col)) * 32 + quad * 8);
            acc[nt] = __builtin_amdgcn_mfma_f32_16x16x32_bf16(af, bf, acc[nt], 0, 0, 0);
        }
    }
    __syncthreads();   // gl ready

    // ---- x2 (registers) + LN2 stats ----
    float x2r[4][4];
    float s1[4] = {0.f, 0.f, 0.f, 0.f}, s2[4] = {0.f, 0.f, 0.f, 0.f};
    #pragma unroll
    for (int nt = 0; nt < 4; nt++) {
        int col = nh * 64 + nt * 16 + r16;
        float bv = proj_b[col], gv = gl[col];
        #pragma unroll
        for (int reg = 0; reg < 4; reg++) {
            int lr = lr0 + quad * 4 + reg;
            float tv = bf2f(tbuf[(size_t)(row0 + lr) * CC + col]);
            float v = acc[nt][reg] + bv + xs[lr][col] + 0.02f * tv * gv;
            x2r[nt][reg] = v;
            s1[reg] += v; s2[reg] += v * v;
        }
    }
    #pragma unroll
    for (int reg = 0; reg < 4; reg++) {
        #pragma unroll
        for (int off = 8; off; off >>= 1) {
            s1[reg] += __shfl_xor(s1[reg], off);
            s2[reg] += __shfl_xor(s2[reg], off);
        }
    }
    if (r16 == 0) {
        #pragma unroll
        for (int reg = 0; reg < 4; reg++) {
            S1[w][quad * 4 + reg] = s1[reg];
            S2[w][quad * 4 + reg] = s2[reg];
        }
    }
    __syncthreads();
    const int pw = w ^ 2;   // other col-half, same rows
    float mu[4], rr[4];
    #pragma unroll
    for (int reg = 0; reg < 4; reg++) {
        int r = quad * 4 + reg;
        float t1 = S1[w][r] + S1[pw][r];
        float t2 = S2[w][r] + S2[pw][r];
        mu[reg] = t1 * (1.0f / CC);
        float var = t2 * (1.0f / CC) - mu[reg] * mu[reg];
        rr[reg] = rsqrtf(var + 1e-5f);
    }
    #pragma unroll
    for (int nt = 0; nt < 4; nt++) {
        int col = nh * 64 + nt * 16 + r16;
        float wv = w2[col], bv2 = b2[col];
        #pragma unroll
        for (int reg = 0; reg < 4; reg++) {
            int lr = lr0 + quad * 4 + reg;
            ln2l[lr][col] = f2bf((x2r[nt][reg] - mu[reg]) * rr[reg] * wv + bv2);
        }
    }
    __syncthreads();   // ln2l ready

    // ---- fc1: wave = 16 rows x 256 cols (cols nh*256..), gelu -> hl ----
    short8 af1[4];
    #pragma unroll
    for (int ks = 0; ks < 4; ks++)
        af1[ks] = *(const short8*)&ln2l[lr0 + r16][ks * 32 + quad * 8];
    #pragma unroll
    for (int g = 0; g < 4; g++) {
        floatx4 a2[4] = {};
        #pragma unroll
        for (int ks = 0; ks < 4; ks++) {
            #pragma unroll
            for (int nt = 0; nt < 4; nt++) {
                int col = nh * 256 + g * 64 + nt * 16 + r16;
                short8 bf = *(const short8*)(fc1T2 + ((size_t)(ks * 512 + col)) * 32 + quad * 8);
                a2[nt] = __builtin_amdgcn_mfma_f32_16x16x32_bf16(af1[ks], bf, a2[nt], 0, 0, 0);
            }
        }
        #pragma unroll
        for (int nt = 0; nt < 4; nt++) {
            int col = nh * 256 + g * 64 + nt * 16 + r16;
            float bv = fc1_b[col];
            #pragma unroll
            for (int reg = 0; reg < 4; reg++) {
                int lr = lr0 + quad * 4 + reg;
                hl[lr][col] = f2bf(gelu_f(a2[nt][reg] + bv));
            }
        }
    }
    __syncthreads();   // hl ready

    // ---- fc2: wave = 16 rows x 64 cols (cols nh*64..), K=512 ----
    floatx4 a3[4] = {};
    #pragma unroll
    for (int ks = 0; ks < 16; ks++) {
        short8 af = *(const short8*)&hl[lr0 + r16][ks * 32 + quad * 8];
        #pragma unroll
        for (int nt = 0; nt < 4; nt++) {
            int col = nh * 64 + nt * 16 + r16;
            short8 bf = *(const short8*)(fc2T2 + ((size_t)(ks * 128 + col)) * 32 + quad * 8);
            a3[nt] = __builtin_amdgcn_mfma_f32_16x16x32_bf16(af, bf, a3[nt], 0, 0, 0);
        }
    }
    #pragma unroll
    for (int nt = 0; nt < 4; nt++) {
        int col = nh * 64 + nt * 16 + r16;
        float bv = fc2_b[col];
        #pragma unroll
        for (int reg = 0; reg < 4; reg++) {
            int lr = lr0 + quad * 4 + reg;
            st[col][lr] = a3[nt][reg] + bv + x2r[nt][reg];
        }
    }
    __syncthreads();
    // ---- coalesced NCHW store: 128 cols x 32 p ----
    {
        int col = t >> 1, ch = (t & 1) * 16;
        float* dst = out + (size_t)(n * CC + col) * HW + p0 + ch;
        #pragma unroll
        for (int u = 0; u < 4; u++) {
            float4 v;
            v.x = st[col][ch + u * 4 + 0];
            v.y = st[col][ch + u * 4 + 1];
            v.z = st[col][ch + u * 4 + 2];
            v.w = st[col][ch + u * 4 + 3];
            *(float4*)(dst + u * 4) = v;
        }
    }
}

extern "C" void kernel_launch(void* const* d_in, const int* in_sizes, int n_in,
                              void* d_out, int out_size, void* d_ws, size_t ws_size,
                              hipStream_t stream)
{
    const float* x       = (const float*)d_in[0];
    const float* ln1_w   = (const float*)d_in[1];
    const float* ln1_b   = (const float*)d_in[2];
    const float* ln2_w   = (const float*)d_in[3];
    const float* ln2_b   = (const float*)d_in[4];
    const float* qkv_w   = (const float*)d_in[5];
    const float* qkv_b   = (const float*)d_in[6];
    const float* proj_w  = (const float*)d_in[7];
    const float* proj_b  = (const float*)d_in[8];
    const float* rpb     = (const float*)d_in[9];
    const float* conv1_w = (const float*)d_in[10];
    const float* conv1_b = (const float*)d_in[11];
    const float* conv2_w = (const float*)d_in[12];
    const float* conv2_b = (const float*)d_in[13];
    const float* ca1_w   = (const float*)d_in[14];
    const float* ca1_b   = (const float*)d_in[15];
    const float* ca2_w   = (const float*)d_in[16];
    const float* ca2_b   = (const float*)d_in[17];
    const float* fc1_w   = (const float*)d_in[18];
    const float* fc1_b   = (const float*)d_in[19];
    const float* fc2_w   = (const float*)d_in[20];
    const float* fc2_b   = (const float*)d_in[21];
    float* out = (float*)d_out;

    char* ws = (char*)d_ws;
    BF*    xn_bf   = (BF*)(ws);                  // M*128*2 = 4 MB
    BF*    qkv_bf  = (BF*)(ws + 4194304);        // M*384*2 = 12 MB
    BF*    t_bf    = (BF*)(ws + 16777216);       // M*128*2 = 4 MB
    BF*    na_bf   = (BF*)(ws + 20971520);       // M*128*2 = 4 MB
    float* part    = (float*)(ws + 25165824);    // 2 KB
    BF*    qkvT    = (BF*)(ws + 25167872);       // 98304 B
    BF*    c1T     = (BF*)(ws + 25266176);       // 8192 B
    BF*    c2T     = (BF*)(ws + 25274368);       // 8192 B
    BF*    projT2  = (BF*)(ws + 25282560);       // 32768 B
    BF*    fc1T2   = (BF*)(ws + 25315328);       // 131072 B
    BF*    fc2T2   = (BF*)(ws + 25446400);       // 131072 B

    // 1. LN1 transpose-tile + one-time weight prep (blocks 512..639)
    ln1t_kernel<<<640, 256, 0, stream>>>(x, ln1_w, ln1_b, xn_bf, part,
        qkv_w, conv1_w, conv2_w, proj_w, fc1_w, fc2_w,
        qkvT, c1T, c2T, projT2, fc1T2, fc2T2);
    // 2. qkv GEMM + conv-MLP (+column sums), one launch
    phase2<<<1792, 256, 0, stream>>>(xn_bf, qkvT, qkv_b, qkv_bf,
                                     c1T, conv1_b, c2T, conv2_b, t_bf, part);
    // 3. MFMA neighborhood attention
    na_mfma_kernel<<<1024, 256, 0, stream>>>(qkv_bf, rpb, na_bf);
    // 4. fused tail: CA gate + proj + x2 + LN2 + fc1 + fc2 + NCHW store
    tail_kernel<<<512, 256, 0, stream>>>(na_bf, projT2, proj_b, x, t_bf, part,
                                         ca1_w, ca1_b, ca2_w, ca2_b,
                                         ln2_w, ln2_b, fc1T2, fc1_b,
                                         fc2T2, fc2_b, out);
}